// Round 2
// baseline (1064.572 us; speedup 1.0000x reference)
//
#include <hip/hip_runtime.h>

typedef __bf16 bf16;
typedef bf16 bf16x8 __attribute__((ext_vector_type(8)));
typedef bf16 bf16x4 __attribute__((ext_vector_type(4)));
typedef float f32x4 __attribute__((ext_vector_type(4)));

// ---------------------------------------------------------------------------
// async global->LDS 16B copy (wave-uniform LDS base + lane*16 placement)
// ---------------------------------------------------------------------------
static __device__ __forceinline__ void async16(const void* g, void* l) {
  __builtin_amdgcn_global_load_lds((__attribute__((address_space(1))) void*)g,
                                   (__attribute__((address_space(3))) void*)l,
                                   16, 0, 0);
}

// ---------------------------------------------------------------------------
// Weight f32 -> bf16 conversion (ternary {-1,0,1}: exact in bf16).
// Virtual concatenation: [0,4M) Wq|Wk|Wv|Wo (1M each), [4M,8M) Wff1,
// [8M,12M) Wff2.  One thread = 4 elements (float4 load, 8B store).
// ---------------------------------------------------------------------------
__global__ __launch_bounds__(256) void cvt_weights(
    const float* __restrict__ Wq, const float* __restrict__ Wk,
    const float* __restrict__ Wv, const float* __restrict__ Wo,
    const float* __restrict__ Wf1, const float* __restrict__ Wf2,
    bf16* __restrict__ dst) {
  const size_t i = ((size_t)blockIdx.x * 256 + threadIdx.x) * 4;
  const size_t M1 = 1u << 20;
  const float* src;
  size_t off;
  if (i < 4 * M1) {
    const int w = (int)(i >> 20);
    src = (w == 0) ? Wq : (w == 1) ? Wk : (w == 2) ? Wv : Wo;
    off = i & (M1 - 1);
  } else if (i < 8 * M1) {
    src = Wf1;
    off = i - 4 * M1;
  } else {
    src = Wf2;
    off = i - 8 * M1;
  }
  const float4 v = *(const float4*)(src + off);
  bf16x4 o = {(bf16)v.x, (bf16)v.y, (bf16)v.z, (bf16)v.w};
  *(bf16x4*)(dst + i) = o;
}

// ---------------------------------------------------------------------------
// GEMM: C[M,N] = A[M,K] * B[N,K]^T  (+ optional second A accumulated, epilogue)
// EPI: 0 = f32 store, 2 = f32(acc + R[f32]), 3 = bf16 gelu(acc)
// 128x128 tile, BK=32, 256 threads = 4 waves (2x2 of 64x64), mfma 16x16x32 bf16
// ---------------------------------------------------------------------------
template <int EPI, bool SPLIT>
static __device__ __forceinline__ void gemm_body(
    const bf16* __restrict__ A, const bf16* __restrict__ A2,
    const bf16* __restrict__ B, void* __restrict__ Cv,
    const float* __restrict__ R, int col0, int row0, int M, int N, int K) {
  __shared__ bf16 sA[128 * 32];
  __shared__ bf16 sB[128 * 32];
  const int tid = threadIdx.x;
  const int lane = tid & 63;
  const int wid = tid >> 6;
  const int wm = wid >> 1, wn = wid & 1;

  f32x4 acc[4][4];
  const f32x4 fzero = {0.f, 0.f, 0.f, 0.f};
#pragma unroll
  for (int i = 0; i < 4; ++i)
#pragma unroll
    for (int j = 0; j < 4; ++j) acc[i][j] = fzero;

  const int nk = K >> 5;
  const int total = SPLIT ? (nk << 1) : nk;
  // per-thread staging chunks (16B each): chunk c covers row c>>2, cols (c&3)*8
  const int r0 = tid >> 2, c0 = (tid & 3) << 3;
  const int r1 = (256 + tid) >> 2, c1 = ((256 + tid) & 3) << 3;
  bf16* lA0 = sA + (wid << 6) * 8;  // wave-uniform LDS bases
  bf16* lA1 = sA + (256 + (wid << 6)) * 8;
  bf16* lB0 = sB + (wid << 6) * 8;
  bf16* lB1 = sB + (256 + (wid << 6)) * 8;

  for (int kt = 0; kt < total; ++kt) {
    const int kk = (kt < nk) ? kt : kt - nk;
    const bf16* Ap = (SPLIT && kt >= nk) ? A2 : A;
    const int k0 = kk << 5;
    async16(Ap + (size_t)(row0 + r0) * K + k0 + c0, lA0);
    async16(Ap + (size_t)(row0 + r1) * K + k0 + c1, lA1);
    async16(B + (size_t)(col0 + r0) * K + k0 + c0, lB0);
    async16(B + (size_t)(col0 + r1) * K + k0 + c1, lB1);
    __syncthreads();
    const int fr = lane & 15, fq = (lane >> 4) << 3;
    bf16x8 af[4], bfr[4];
#pragma unroll
    for (int i = 0; i < 4; ++i)
      af[i] = *(const bf16x8*)&sA[(wm * 64 + i * 16 + fr) * 32 + fq];
#pragma unroll
    for (int j = 0; j < 4; ++j)
      bfr[j] = *(const bf16x8*)&sB[(wn * 64 + j * 16 + fr) * 32 + fq];
#pragma unroll
    for (int i = 0; i < 4; ++i)
#pragma unroll
      for (int j = 0; j < 4; ++j)
        acc[i][j] = __builtin_amdgcn_mfma_f32_16x16x32_bf16(af[i], bfr[j],
                                                            acc[i][j], 0, 0, 0);
    __syncthreads();
  }

  // C/D layout (m89-verified): col = lane&15, row = (lane>>4)*4 + reg
  const int fr = lane & 15, fq4 = (lane >> 4) << 2;
#pragma unroll
  for (int i = 0; i < 4; ++i) {
#pragma unroll
    for (int j = 0; j < 4; ++j) {
      const int rbase = row0 + wm * 64 + i * 16 + fq4;
      const int col = col0 + wn * 64 + j * 16 + fr;
#pragma unroll
      for (int r = 0; r < 4; ++r) {
        const size_t idx = (size_t)(rbase + r) * N + col;
        const float val = acc[i][j][r];
        if constexpr (EPI == 0) {
          ((float*)Cv)[idx] = val;
        } else if constexpr (EPI == 2) {
          ((float*)Cv)[idx] = val + R[idx];
        } else {  // EPI == 3: exact GELU -> bf16
          ((bf16*)Cv)[idx] =
              (bf16)(0.5f * val * (1.0f + erff(val * 0.7071067811865476f)));
        }
      }
    }
  }
}

template <int EPI, bool SPLIT>
__global__ __launch_bounds__(256) void gemm_bt(
    const bf16* __restrict__ A, const bf16* __restrict__ A2,
    const bf16* __restrict__ B, void* __restrict__ Cv,
    const float* __restrict__ R, int M, int N, int K) {
  gemm_body<EPI, SPLIT>(A, A2, B, Cv, R, blockIdx.x * 128, blockIdx.y * 128, M,
                        N, K);
}

// QKV fused: grid (24, 32); blockIdx.x>>3 selects {q,k,v}
__global__ __launch_bounds__(256) void gemm_qkv(
    const bf16* __restrict__ A, const bf16* __restrict__ A2,
    const bf16* __restrict__ Bq, const bf16* __restrict__ Bk,
    const bf16* __restrict__ Bv, float* Cq, float* Ck, float* Cvv) {
  const int which = blockIdx.x >> 3;
  const bf16* B = (which == 0) ? Bq : ((which == 1) ? Bk : Bv);
  float* C = (which == 0) ? Cq : ((which == 1) ? Ck : Cvv);
  gemm_body<0, true>(A, A2, B, (void*)C, nullptr, (blockIdx.x & 7) * 128,
                     blockIdx.y * 128, 4096, 1024, 1024);
}

// ---------------------------------------------------------------------------
// LayerNorm over D=1024 (f32 input), one block per row. SPLIT: emit bf16 hi +
// lo halves so hi+lo tracks the f32 LN output to ~2^-17 (needed for the
// argmax-sharp softmax); otherwise single bf16 output.
// ---------------------------------------------------------------------------
template <bool SPLIT>
__global__ __launch_bounds__(256) void ln_kernel(
    const float* __restrict__ x, const float* __restrict__ g,
    const float* __restrict__ b, bf16* __restrict__ hi, bf16* __restrict__ lo) {
  const int row = blockIdx.x;
  const int tid = threadIdx.x;
  const float* xr = x + (size_t)row * 1024;
  float v[4];
  float s1 = 0.f, s2 = 0.f;
#pragma unroll
  for (int j = 0; j < 4; ++j) {
    v[j] = xr[j * 256 + tid];
    s1 += v[j];
    s2 += v[j] * v[j];
  }
#pragma unroll
  for (int off = 1; off < 64; off <<= 1) {
    s1 += __shfl_xor(s1, off);
    s2 += __shfl_xor(s2, off);
  }
  __shared__ float ws1[4], ws2[4];
  const int wid = tid >> 6;
  if ((tid & 63) == 0) {
    ws1[wid] = s1;
    ws2[wid] = s2;
  }
  __syncthreads();
  s1 = ws1[0] + ws1[1] + ws1[2] + ws1[3];
  s2 = ws2[0] + ws2[1] + ws2[2] + ws2[3];
  const float mu = s1 * (1.f / 1024.f);
  const float var = s2 * (1.f / 1024.f) - mu * mu;
  const float rstd = 1.0f / sqrtf(var + 1e-5f);
#pragma unroll
  for (int j = 0; j < 4; ++j) {
    const int cc = j * 256 + tid;
    const float y = (v[j] - mu) * rstd * g[cc] + b[cc];
    const bf16 yh = (bf16)y;
    hi[(size_t)row * 1024 + cc] = yh;
    if constexpr (SPLIT) lo[(size_t)row * 1024 + cc] = (bf16)(y - (float)yh);
  }
}

// ---------------------------------------------------------------------------
// Causal flash attention, f32 VALU. Block = 256 threads = one (b, h, 64-query
// tile). Lane map: tx=tid&15 (stride-16 keys/dims), ty=tid>>4 (stride-16
// queries) -> all LDS float4 reads are broadcast or 2-way (free).
// P overwrites the K tile (saves 17KB LDS -> 52.2KB total, 3 blocks/CU).
// ---------------------------------------------------------------------------
__global__ __launch_bounds__(256) void attn_kernel(
    const float* __restrict__ qg, const float* __restrict__ kg,
    const float* __restrict__ vg, bf16* __restrict__ out) {
  __shared__ float Qs[64 * 68];
  __shared__ float KP[64 * 68];  // K tile, then reused as P tile
  __shared__ float Vt[64 * 68];  // V transposed: Vt[d][k]
  const int bid = blockIdx.x;
  const int qt = bid & 31;
  const int h = (bid >> 5) & 15;
  const int b = bid >> 9;
  const int t0 = qt << 6;
  const int tid = threadIdx.x;
  const int tx = tid & 15, ty = tid >> 4;

  const size_t bq = ((size_t)(b * 2048 + t0)) * 1024 + h * 64;
#pragma unroll
  for (int it = 0; it < 16; ++it) {
    const int idx = it * 256 + tid;
    const int r = idx >> 6, c = idx & 63;
    Qs[r * 68 + c] = qg[bq + (size_t)r * 1024 + c] * 0.125f;  // fold 1/sqrt(64)
  }
  float o[4][4];
#pragma unroll
  for (int i = 0; i < 4; ++i)
#pragma unroll
    for (int j = 0; j < 4; ++j) o[i][j] = 0.f;
  float m_i[4] = {-3e38f, -3e38f, -3e38f, -3e38f};
  float l_i[4] = {0.f, 0.f, 0.f, 0.f};
  __syncthreads();

  for (int kt = 0; kt <= qt; ++kt) {
    const int kb = kt << 6;
    const size_t bk = ((size_t)(b * 2048 + kb)) * 1024 + h * 64;
#pragma unroll
    for (int it = 0; it < 16; ++it) {
      const int idx = it * 256 + tid;
      const int r = idx >> 6, c = idx & 63;
      KP[r * 68 + c] = kg[bk + (size_t)r * 1024 + c];
      Vt[c * 68 + r] = vg[bk + (size_t)r * 1024 + c];
    }
    __syncthreads();

    float s[4][4];
#pragma unroll
    for (int i = 0; i < 4; ++i)
#pragma unroll
      for (int j = 0; j < 4; ++j) s[i][j] = 0.f;
    for (int d = 0; d < 64; d += 4) {
      float4 qa[4], ka[4];
#pragma unroll
      for (int i = 0; i < 4; ++i)
        qa[i] = *(const float4*)&Qs[(ty + 16 * i) * 68 + d];
#pragma unroll
      for (int j = 0; j < 4; ++j)
        ka[j] = *(const float4*)&KP[(tx + 16 * j) * 68 + d];
#pragma unroll
      for (int i = 0; i < 4; ++i)
#pragma unroll
        for (int j = 0; j < 4; ++j)
          s[i][j] += qa[i].x * ka[j].x + qa[i].y * ka[j].y + qa[i].z * ka[j].z +
                     qa[i].w * ka[j].w;
    }
    // causal mask (strict upper)
#pragma unroll
    for (int i = 0; i < 4; ++i)
#pragma unroll
      for (int j = 0; j < 4; ++j)
        if (kb + tx + 16 * j > t0 + ty + 16 * i) s[i][j] = -3e38f;

    __syncthreads();  // all K reads done; KP becomes P

    float al[4], p[4][4];
#pragma unroll
    for (int i = 0; i < 4; ++i) {
      float mt = fmaxf(fmaxf(s[i][0], s[i][1]), fmaxf(s[i][2], s[i][3]));
#pragma unroll
      for (int off = 1; off < 16; off <<= 1) mt = fmaxf(mt, __shfl_xor(mt, off));
      const float mn = fmaxf(m_i[i], mt);
      al[i] = expf(m_i[i] - mn);
      float ps = 0.f;
#pragma unroll
      for (int j = 0; j < 4; ++j) {
        p[i][j] = expf(s[i][j] - mn);
        ps += p[i][j];
      }
#pragma unroll
      for (int off = 1; off < 16; off <<= 1) ps += __shfl_xor(ps, off);
      l_i[i] = l_i[i] * al[i] + ps;
      m_i[i] = mn;
#pragma unroll
      for (int j = 0; j < 4; ++j) {
        KP[(ty + 16 * i) * 68 + tx + 16 * j] = p[i][j];
        o[i][j] *= al[i];
      }
    }
    __syncthreads();  // P visible

    for (int k2 = 0; k2 < 64; k2 += 4) {
      float4 pr[4], vr[4];
#pragma unroll
      for (int i = 0; i < 4; ++i)
        pr[i] = *(const float4*)&KP[(ty + 16 * i) * 68 + k2];
#pragma unroll
      for (int j = 0; j < 4; ++j)
        vr[j] = *(const float4*)&Vt[(tx + 16 * j) * 68 + k2];
#pragma unroll
      for (int i = 0; i < 4; ++i)
#pragma unroll
        for (int j = 0; j < 4; ++j)
          o[i][j] += pr[i].x * vr[j].x + pr[i].y * vr[j].y + pr[i].z * vr[j].z +
                     pr[i].w * vr[j].w;
    }
    __syncthreads();  // PV reads done before next tile's staging
  }

#pragma unroll
  for (int i = 0; i < 4; ++i) {
    const float inv = 1.0f / l_i[i];
#pragma unroll
    for (int j = 0; j < 4; ++j) {
      const size_t oi =
          ((size_t)(b * 2048 + t0 + ty + 16 * i)) * 1024 + h * 64 + tx + 16 * j;
      out[oi] = (bf16)(o[i][j] * inv);
    }
  }
}

// ---------------------------------------------------------------------------
extern "C" void kernel_launch(void* const* d_in, const int* in_sizes, int n_in,
                              void* d_out, int out_size, void* d_ws,
                              size_t ws_size, hipStream_t stream) {
  const float* x = (const float*)d_in[0];
  // d_in[1] = mask: causal triu, recomputed from indices — ignored
  const float* g1 = (const float*)d_in[2];
  const float* b1 = (const float*)d_in[3];
  const float* g2 = (const float*)d_in[4];
  const float* b2 = (const float*)d_in[5];
  const float* Wq = (const float*)d_in[6];
  const float* Wk = (const float*)d_in[7];
  const float* Wv = (const float*)d_in[8];
  const float* Wo = (const float*)d_in[9];
  const float* Wf1 = (const float*)d_in[10];
  const float* Wf2 = (const float*)d_in[11];
  char* ws = (char*)d_ws;
  const size_t MB = 1024 * 1024;
  const size_t M1 = 1u << 20;  // elements
  // [0,24MiB): bf16 weights  Wq|Wk|Wv|Wo|Wff1|Wff2
  bf16* wbf = (bf16*)ws;
  bf16* Wq_b = wbf + 0 * M1;
  bf16* Wk_b = wbf + 1 * M1;
  bf16* Wv_b = wbf + 2 * M1;
  bf16* Wo_b = wbf + 3 * M1;
  bf16* Wf1_b = wbf + 4 * M1;
  bf16* Wf2_b = wbf + 8 * M1;
  bf16* h_hi = (bf16*)(ws + 24 * MB);   // 8 MiB
  bf16* h_lo = (bf16*)(ws + 32 * MB);   // 8 MiB
  float* qb = (float*)(ws + 40 * MB);   // 16 MiB
  float* kb = (float*)(ws + 56 * MB);   // 16 MiB
  float* vb = (float*)(ws + 72 * MB);   // 16 MiB
  bf16* attnout = (bf16*)(ws + 88 * MB);  // 8 MiB
  float* x1 = (float*)(ws + 96 * MB);     // 16 MiB (peak: 112 MiB)
  bf16* h2 = attnout;                   // alias: attnout dead after Wo GEMM
  bf16* ff = (bf16*)(ws + 40 * MB);     // alias: q/k dead after attention
  float* outp = (float*)d_out;

  // 0) weights f32 -> bf16 (exact for ternary values)
  cvt_weights<<<12288, 256, 0, stream>>>(Wq, Wk, Wv, Wo, Wf1, Wf2, wbf);
  // 1) LN1 -> split bf16 hi/lo
  ln_kernel<true><<<4096, 256, 0, stream>>>(x, g1, b1, h_hi, h_lo);
  // 2) Q,K,V = (h_hi+h_lo) @ W^T, f32 outputs (fused, 768 blocks)
  gemm_qkv<<<dim3(24, 32), 256, 0, stream>>>(h_hi, h_lo, Wq_b, Wk_b, Wv_b, qb,
                                             kb, vb);
  // 3) causal flash attention (f32), bf16 out in (B,T,H*DH) layout
  attn_kernel<<<1024, 256, 0, stream>>>(qb, kb, vb, attnout);
  // 4) x1 = x + attnout @ Wo^T   (f32)
  gemm_bt<2, false><<<dim3(8, 32), 256, 0, stream>>>(
      attnout, nullptr, Wo_b, (void*)x1, x, 4096, 1024, 1024);
  // 5) LN2 -> h2 (bf16)
  ln_kernel<false><<<4096, 256, 0, stream>>>(x1, g2, b2, h2, nullptr);
  // 6) ff = gelu(h2 @ Wff1^T)  (bf16)
  gemm_bt<3, false><<<dim3(32, 32), 256, 0, stream>>>(
      h2, nullptr, Wf1_b, (void*)ff, nullptr, 4096, 4096, 1024);
  // 7) out = x1 + ff @ Wff2^T  (f32)
  gemm_bt<2, false><<<dim3(8, 32), 256, 0, stream>>>(
      ff, nullptr, Wf2_b, (void*)outp, x1, 4096, 1024, 4096);
}

// Round 4
// 497.480 us; speedup vs baseline: 2.1399x; 2.1399x over previous
//
#include <hip/hip_runtime.h>

typedef __bf16 bf16;
typedef bf16 bf16x8 __attribute__((ext_vector_type(8)));
typedef bf16 bf16x4 __attribute__((ext_vector_type(4)));
typedef float f32x4 __attribute__((ext_vector_type(4)));

// ---------------------------------------------------------------------------
// async global->LDS 16B copy (wave-uniform LDS base + lane*16 placement)
// ---------------------------------------------------------------------------
static __device__ __forceinline__ void async16(const void* g, void* l) {
  __builtin_amdgcn_global_load_lds((__attribute__((address_space(1))) void*)g,
                                   (__attribute__((address_space(3))) void*)l,
                                   16, 0, 0);
}

// ---------------------------------------------------------------------------
// Weight f32 -> bf16 conversion (ternary {-1,0,1}: exact in bf16).
// cvt4: Wq|Wk|Wv|Wo (1M el each) -> dst[0..4M).  grid 4096.
// cvt2: Wf1|Wf2   (4M el each)  -> dst[0..8M).  grid 8192 (runs after h dies).
// ---------------------------------------------------------------------------
__global__ __launch_bounds__(256) void cvt4(const float* __restrict__ a,
                                            const float* __restrict__ b,
                                            const float* __restrict__ c,
                                            const float* __restrict__ d,
                                            bf16* __restrict__ dst) {
  const size_t i = ((size_t)blockIdx.x * 256 + threadIdx.x) * 4;
  const size_t M1 = 1u << 20;
  const float* src = (i < M1) ? a : (i < 2 * M1) ? b : (i < 3 * M1) ? c : d;
  const size_t off = i & (M1 - 1);
  const float4 v = *(const float4*)(src + off);
  bf16x4 o = {(bf16)v.x, (bf16)v.y, (bf16)v.z, (bf16)v.w};
  *(bf16x4*)(dst + i) = o;
}

__global__ __launch_bounds__(256) void cvt2(const float* __restrict__ a,
                                            const float* __restrict__ b,
                                            bf16* __restrict__ dst) {
  const size_t i = ((size_t)blockIdx.x * 256 + threadIdx.x) * 4;
  const size_t M4 = 4u << 20;
  const float* src = (i < M4) ? a : b;
  const size_t off = (i < M4) ? i : i - M4;
  const float4 v = *(const float4*)(src + off);
  bf16x4 o = {(bf16)v.x, (bf16)v.y, (bf16)v.z, (bf16)v.w};
  *(bf16x4*)(dst + i) = o;
}

// ---------------------------------------------------------------------------
// GEMM: C[M,N] = A[M,K] * B[N,K]^T  (+ optional second A accumulated, epilogue)
// EPI: 0 = f32 store, 2 = f32(acc + R[f32]), 3 = bf16 gelu(acc),
//      4 = split bf16 hi/lo of (acc*scale)  (Cv=hi, C2=lo),
//      5 = bf16 store transposed to V^T global layout (b,h,d,t)
// 128x128 tile, BK=32, 256 threads = 4 waves (2x2 of 64x64), mfma 16x16x32 bf16
// ---------------------------------------------------------------------------
template <int EPI, bool SPLIT>
static __device__ __forceinline__ void gemm_body(
    const bf16* __restrict__ A, const bf16* __restrict__ A2,
    const bf16* __restrict__ B, void* __restrict__ Cv, void* __restrict__ C2,
    const float* __restrict__ R, float scale, int col0, int row0, int M, int N,
    int K) {
  __shared__ bf16 sA[128 * 32];
  __shared__ bf16 sB[128 * 32];
  const int tid = threadIdx.x;
  const int lane = tid & 63;
  const int wid = tid >> 6;
  const int wm = wid >> 1, wn = wid & 1;

  f32x4 acc[4][4];
  const f32x4 fzero = {0.f, 0.f, 0.f, 0.f};
#pragma unroll
  for (int i = 0; i < 4; ++i)
#pragma unroll
    for (int j = 0; j < 4; ++j) acc[i][j] = fzero;

  const int nk = K >> 5;
  const int total = SPLIT ? (nk << 1) : nk;
  const int r0 = tid >> 2, c0 = (tid & 3) << 3;
  const int r1 = (256 + tid) >> 2, c1 = ((256 + tid) & 3) << 3;
  bf16* lA0 = sA + (wid << 6) * 8;  // wave-uniform LDS bases
  bf16* lA1 = sA + (256 + (wid << 6)) * 8;
  bf16* lB0 = sB + (wid << 6) * 8;
  bf16* lB1 = sB + (256 + (wid << 6)) * 8;

  for (int kt = 0; kt < total; ++kt) {
    const int kk = (kt < nk) ? kt : kt - nk;
    const bf16* Ap = (SPLIT && kt >= nk) ? A2 : A;
    const int k0 = kk << 5;
    async16(Ap + (size_t)(row0 + r0) * K + k0 + c0, lA0);
    async16(Ap + (size_t)(row0 + r1) * K + k0 + c1, lA1);
    async16(B + (size_t)(col0 + r0) * K + k0 + c0, lB0);
    async16(B + (size_t)(col0 + r1) * K + k0 + c1, lB1);
    __syncthreads();
    const int fr = lane & 15, fq = (lane >> 4) << 3;
    bf16x8 af[4], bfr[4];
#pragma unroll
    for (int i = 0; i < 4; ++i)
      af[i] = *(const bf16x8*)&sA[(wm * 64 + i * 16 + fr) * 32 + fq];
#pragma unroll
    for (int j = 0; j < 4; ++j)
      bfr[j] = *(const bf16x8*)&sB[(wn * 64 + j * 16 + fr) * 32 + fq];
#pragma unroll
    for (int i = 0; i < 4; ++i)
#pragma unroll
      for (int j = 0; j < 4; ++j)
        acc[i][j] = __builtin_amdgcn_mfma_f32_16x16x32_bf16(af[i], bfr[j],
                                                            acc[i][j], 0, 0, 0);
    __syncthreads();
  }

  // C/D layout (m89-verified): col = lane&15, row = (lane>>4)*4 + reg
  const int fr = lane & 15, fq4 = (lane >> 4) << 2;
#pragma unroll
  for (int i = 0; i < 4; ++i) {
#pragma unroll
    for (int j = 0; j < 4; ++j) {
      const int rbase = row0 + wm * 64 + i * 16 + fq4;
      const int col = col0 + wn * 64 + j * 16 + fr;
      if constexpr (EPI == 5) {
        // V^T global: (b, h, d, t); rows rbase..rbase+3 are consecutive t
        const int b = rbase >> 11, t = rbase & 2047;
        const int hh = col >> 6, d = col & 63;
        bf16x4 o4 = {(bf16)acc[i][j][0], (bf16)acc[i][j][1],
                     (bf16)acc[i][j][2], (bf16)acc[i][j][3]};
        *(bf16x4*)&((bf16*)Cv)[(((size_t)(b * 16 + hh)) * 64 + d) * 2048 + t] =
            o4;
      } else {
#pragma unroll
        for (int r = 0; r < 4; ++r) {
          const size_t idx = (size_t)(rbase + r) * N + col;
          const float val = acc[i][j][r];
          if constexpr (EPI == 0) {
            ((float*)Cv)[idx] = val;
          } else if constexpr (EPI == 2) {
            ((float*)Cv)[idx] = val + R[idx];
          } else if constexpr (EPI == 3) {
            ((bf16*)Cv)[idx] =
                (bf16)(0.5f * val * (1.0f + erff(val * 0.7071067811865476f)));
          } else {  // EPI == 4: split hi/lo bf16 of val*scale
            const float vs = val * scale;
            const bf16 hi = (bf16)vs;
            ((bf16*)Cv)[idx] = hi;
            ((bf16*)C2)[idx] = (bf16)(vs - (float)hi);
          }
        }
      }
    }
  }
}

template <int EPI, bool SPLIT>
__global__ __launch_bounds__(256) void gemm_bt(
    const bf16* __restrict__ A, const bf16* __restrict__ A2,
    const bf16* __restrict__ B, void* __restrict__ Cv,
    const float* __restrict__ R, int M, int N, int K) {
  gemm_body<EPI, SPLIT>(A, A2, B, Cv, nullptr, R, 1.0f, blockIdx.x * 128,
                        blockIdx.y * 128, M, N, K);
}

// Q,K fused: grid (16, 32); blockIdx.x>>3 selects q (scaled 1/8) or k.
__global__ __launch_bounds__(256) void gemm_qk(
    const bf16* __restrict__ A, const bf16* __restrict__ A2,
    const bf16* __restrict__ Bq, const bf16* __restrict__ Bk, bf16* qh,
    bf16* ql, bf16* kh, bf16* kl) {
  const int which = blockIdx.x >> 3;
  gemm_body<4, true>(A, A2, which ? Bk : Bq, which ? (void*)kh : (void*)qh,
                     which ? (void*)kl : (void*)ql, nullptr,
                     which ? 1.0f : 0.125f, (blockIdx.x & 7) * 128,
                     blockIdx.y * 128, 4096, 1024, 1024);
}

// V with transposed store: grid (8, 32)
__global__ __launch_bounds__(256) void gemm_v(const bf16* __restrict__ A,
                                              const bf16* __restrict__ A2,
                                              const bf16* __restrict__ Bv,
                                              bf16* vt) {
  gemm_body<5, true>(A, A2, Bv, (void*)vt, nullptr, nullptr, 1.0f,
                     (blockIdx.x & 7) * 128, blockIdx.y * 128, 4096, 1024,
                     1024);
}

// ---------------------------------------------------------------------------
// LayerNorm over D=1024 (f32 input), one block per row.
// ---------------------------------------------------------------------------
template <bool SPLIT>
__global__ __launch_bounds__(256) void ln_kernel(
    const float* __restrict__ x, const float* __restrict__ g,
    const float* __restrict__ b, bf16* __restrict__ hi, bf16* __restrict__ lo) {
  const int row = blockIdx.x;
  const int tid = threadIdx.x;
  const float* xr = x + (size_t)row * 1024;
  float v[4];
  float s1 = 0.f, s2 = 0.f;
#pragma unroll
  for (int j = 0; j < 4; ++j) {
    v[j] = xr[j * 256 + tid];
    s1 += v[j];
    s2 += v[j] * v[j];
  }
#pragma unroll
  for (int off = 1; off < 64; off <<= 1) {
    s1 += __shfl_xor(s1, off);
    s2 += __shfl_xor(s2, off);
  }
  __shared__ float ws1[4], ws2[4];
  const int wid = tid >> 6;
  if ((tid & 63) == 0) {
    ws1[wid] = s1;
    ws2[wid] = s2;
  }
  __syncthreads();
  s1 = ws1[0] + ws1[1] + ws1[2] + ws1[3];
  s2 = ws2[0] + ws2[1] + ws2[2] + ws2[3];
  const float mu = s1 * (1.f / 1024.f);
  const float var = s2 * (1.f / 1024.f) - mu * mu;
  const float rstd = 1.0f / sqrtf(var + 1e-5f);
#pragma unroll
  for (int j = 0; j < 4; ++j) {
    const int cc = j * 256 + tid;
    const float y = (v[j] - mu) * rstd * g[cc] + b[cc];
    const bf16 yh = (bf16)y;
    hi[(size_t)row * 1024 + cc] = yh;
    if constexpr (SPLIT) lo[(size_t)row * 1024 + cc] = (bf16)(y - (float)yh);
  }
}

// ---------------------------------------------------------------------------
// MFMA causal flash attention. Block = 256 thr = 4 waves = one (b,h,64-query
// tile); wave w owns queries [w*16, w*16+16).  Split-bf16 Q,K:
// S = qh*kh + qh*kl + ql*kh (lo*lo term ~3e-3, below logit-error budget).
// Softmax f32 in registers (C-layout), P -> LDS bf16 (aliases dead K tile,
// with a full barrier between P stores and P/V fragment reads), PV in MFMA
// against V^T tile.  LDS 46080 B -> 3 blocks/CU.
// Long blocks (qt=31) launched first to beat causal imbalance.
// ---------------------------------------------------------------------------
__global__ __launch_bounds__(256) void attn_kernel(
    const bf16* __restrict__ qh_g, const bf16* __restrict__ ql_g,
    const bf16* __restrict__ kh_g, const bf16* __restrict__ kl_g,
    const bf16* __restrict__ vt_g, bf16* __restrict__ out) {
  __shared__ bf16 lds[23040];  // 46080 B
  bf16* Qh = lds;              // 64 x 72
  bf16* Ql = lds + 4608;
  bf16* Kh = lds + 9216;
  bf16* Kl = lds + 13824;
  bf16* Vt = lds + 18432;  // rows = dim d, cols = key (within tile)
  bf16* Ps = Kh;           // alias: P tiles after K is consumed (barriered)

  const int bid = blockIdx.x;
  const int qt = 31 - (bid >> 5);  // long blocks first
  const int h = bid & 15;
  const int b = (bid >> 4) & 1;
  const int t0 = qt << 6;
  const int tid = threadIdx.x;
  const int w = tid >> 6;
  const int lane = tid & 63;
  const int c = lane & 15;
  const int quad = lane >> 4;

  // staging map: chunk idx -> (row idx>>3, col8 (idx&7)*8)
  const int r0 = tid >> 3, c0 = (tid & 7) << 3;
  const int r1 = (tid + 256) >> 3, c1 = ((tid + 256) & 7) << 3;

  const size_t qbase = ((size_t)(b * 2048 + t0)) * 1024 + h * 64;
  *(bf16x8*)&Qh[r0 * 72 + c0] = *(const bf16x8*)&qh_g[qbase + (size_t)r0 * 1024 + c0];
  *(bf16x8*)&Qh[r1 * 72 + c1] = *(const bf16x8*)&qh_g[qbase + (size_t)r1 * 1024 + c1];
  *(bf16x8*)&Ql[r0 * 72 + c0] = *(const bf16x8*)&ql_g[qbase + (size_t)r0 * 1024 + c0];
  *(bf16x8*)&Ql[r1 * 72 + c1] = *(const bf16x8*)&ql_g[qbase + (size_t)r1 * 1024 + c1];

  f32x4 o[4];
  const f32x4 fzero = {0.f, 0.f, 0.f, 0.f};
#pragma unroll
  for (int j = 0; j < 4; ++j) o[j] = fzero;
  float m_i[4] = {-3e38f, -3e38f, -3e38f, -3e38f};
  float l_i[4] = {0.f, 0.f, 0.f, 0.f};

  const size_t vtb = ((size_t)(b * 16 + h)) * 64 * 2048;  // + d*2048 + t

  for (int kt = 0; kt <= qt; ++kt) {
    const int kb = kt << 6;
    __syncthreads();  // (A) prev tile's P/V reads complete before restage
    const size_t kbase = ((size_t)(b * 2048 + kb)) * 1024 + h * 64;
    *(bf16x8*)&Kh[r0 * 72 + c0] = *(const bf16x8*)&kh_g[kbase + (size_t)r0 * 1024 + c0];
    *(bf16x8*)&Kh[r1 * 72 + c1] = *(const bf16x8*)&kh_g[kbase + (size_t)r1 * 1024 + c1];
    *(bf16x8*)&Kl[r0 * 72 + c0] = *(const bf16x8*)&kl_g[kbase + (size_t)r0 * 1024 + c0];
    *(bf16x8*)&Kl[r1 * 72 + c1] = *(const bf16x8*)&kl_g[kbase + (size_t)r1 * 1024 + c1];
    *(bf16x8*)&Vt[r0 * 72 + c0] = *(const bf16x8*)&vt_g[vtb + (size_t)r0 * 2048 + kb + c0];
    *(bf16x8*)&Vt[r1 * 72 + c1] = *(const bf16x8*)&vt_g[vtb + (size_t)r1 * 2048 + kb + c1];
    __syncthreads();  // (B) staging visible

    // fragment loads (A row m = c; k-step s covers contraction cols s*32+..)
    const int mrow = (w * 16 + c) * 72;
    bf16x8 aqh[2], aql[2], bkh[4][2], bkl[4][2];
#pragma unroll
    for (int s = 0; s < 2; ++s) {
      aqh[s] = *(const bf16x8*)&Qh[mrow + s * 32 + quad * 8];
      aql[s] = *(const bf16x8*)&Ql[mrow + s * 32 + quad * 8];
    }
#pragma unroll
    for (int j = 0; j < 4; ++j)
#pragma unroll
      for (int s = 0; s < 2; ++s) {
        bkh[j][s] = *(const bf16x8*)&Kh[(j * 16 + c) * 72 + s * 32 + quad * 8];
        bkl[j][s] = *(const bf16x8*)&Kl[(j * 16 + c) * 72 + s * 32 + quad * 8];
      }

    f32x4 s4[4];
#pragma unroll
    for (int j = 0; j < 4; ++j) s4[j] = fzero;
#pragma unroll
    for (int j = 0; j < 4; ++j)
#pragma unroll
      for (int s = 0; s < 2; ++s) {
        s4[j] = __builtin_amdgcn_mfma_f32_16x16x32_bf16(aqh[s], bkh[j][s], s4[j], 0, 0, 0);
        s4[j] = __builtin_amdgcn_mfma_f32_16x16x32_bf16(aqh[s], bkl[j][s], s4[j], 0, 0, 0);
        s4[j] = __builtin_amdgcn_mfma_f32_16x16x32_bf16(aql[s], bkh[j][s], s4[j], 0, 0, 0);
      }

    if (kt == qt) {  // diagonal tile: strict-upper mask (t0 == kb)
#pragma unroll
      for (int j = 0; j < 4; ++j)
#pragma unroll
        for (int r = 0; r < 4; ++r)
          if (j * 16 + c > w * 16 + quad * 4 + r) s4[j][r] = -3e38f;
    }

    float al[4], p[4][4];
#pragma unroll
    for (int r = 0; r < 4; ++r) {
      float mt = fmaxf(fmaxf(s4[0][r], s4[1][r]), fmaxf(s4[2][r], s4[3][r]));
#pragma unroll
      for (int off = 1; off < 16; off <<= 1) mt = fmaxf(mt, __shfl_xor(mt, off));
      const float mn = fmaxf(m_i[r], mt);
      al[r] = __expf(m_i[r] - mn);
      float ps = 0.f;
#pragma unroll
      for (int j = 0; j < 4; ++j) {
        p[r][j] = __expf(s4[j][r] - mn);
        ps += p[r][j];
      }
#pragma unroll
      for (int off = 1; off < 16; off <<= 1) ps += __shfl_xor(ps, off);
      l_i[r] = l_i[r] * al[r] + ps;
      m_i[r] = mn;
#pragma unroll
      for (int j = 0; j < 4; ++j) o[j][r] *= al[r];
    }

    __syncthreads();  // (C) everyone done reading Kh/Kl before P overwrites
    bf16* Pw = Ps + w * 16 * 72;
#pragma unroll
    for (int r = 0; r < 4; ++r)
#pragma unroll
      for (int j = 0; j < 4; ++j)
        Pw[(quad * 4 + r) * 72 + j * 16 + c] = (bf16)p[r][j];

    __syncthreads();  // (D) P stores committed & visible before fragment reads

    bf16x8 ap[2], bv[4][2];
#pragma unroll
    for (int s = 0; s < 2; ++s)
      ap[s] = *(const bf16x8*)&Pw[c * 72 + s * 32 + quad * 8];
#pragma unroll
    for (int j = 0; j < 4; ++j)
#pragma unroll
      for (int s = 0; s < 2; ++s)
        bv[j][s] = *(const bf16x8*)&Vt[(j * 16 + c) * 72 + s * 32 + quad * 8];
#pragma unroll
    for (int j = 0; j < 4; ++j)
#pragma unroll
      for (int s = 0; s < 2; ++s)
        o[j] = __builtin_amdgcn_mfma_f32_16x16x32_bf16(ap[s], bv[j][s], o[j], 0, 0, 0);
  }

#pragma unroll
  for (int r = 0; r < 4; ++r) {
    const float inv = 1.0f / l_i[r];
#pragma unroll
    for (int j = 0; j < 4; ++j) {
      const size_t oi =
          ((size_t)(b * 2048 + t0 + w * 16 + quad * 4 + r)) * 1024 + h * 64 +
          j * 16 + c;
      out[oi] = (bf16)(o[j][r] * inv);
    }
  }
}

// ---------------------------------------------------------------------------
// Workspace plan (80 MiB peak — kept tight in case ws_size is limited; a
// previous 104 MiB layout corrupted post-timing validation, suspected
// overrun into harness allocations):
//   [ 0, 8)   Wq|Wk|Wv|Wo bf16            (live to k7's predecessor k4)
//   [ 8,24)   h_hi|h_lo  -> (after gemm_v) Wf1_b|Wf2_b   (cvt2 overwrite)
//   [24,40)   qh|ql      -> (after attn)   x1 (f32)
//   [40,72)   kh|kl|vt|attnout -> (after k4) ff (bf16 4096x4096)
//   [72,80)   h2
// ---------------------------------------------------------------------------
extern "C" void kernel_launch(void* const* d_in, const int* in_sizes, int n_in,
                              void* d_out, int out_size, void* d_ws,
                              size_t ws_size, hipStream_t stream) {
  const float* x = (const float*)d_in[0];
  const float* g1 = (const float*)d_in[2];
  const float* b1 = (const float*)d_in[3];
  const float* g2 = (const float*)d_in[4];
  const float* b2 = (const float*)d_in[5];
  const float* Wq = (const float*)d_in[6];
  const float* Wk = (const float*)d_in[7];
  const float* Wv = (const float*)d_in[8];
  const float* Wo = (const float*)d_in[9];
  const float* Wf1 = (const float*)d_in[10];
  const float* Wf2 = (const float*)d_in[11];
  char* ws = (char*)d_ws;
  const size_t MB = 1024 * 1024;
  const size_t M1 = 1u << 20;
  bf16* Wq_b = (bf16*)ws;
  bf16* Wk_b = Wq_b + 1 * M1;
  bf16* Wv_b = Wq_b + 2 * M1;
  bf16* Wo_b = Wq_b + 3 * M1;
  bf16* h_hi = (bf16*)(ws + 8 * MB);
  bf16* h_lo = (bf16*)(ws + 16 * MB);
  bf16* Wf1_b = h_hi;  // alias: h dead after gemm_v; cvt2 fills before k6
  bf16* Wf2_b = h_lo;
  bf16* qh = (bf16*)(ws + 24 * MB);
  bf16* ql = (bf16*)(ws + 32 * MB);
  bf16* kh = (bf16*)(ws + 40 * MB);
  bf16* kl = (bf16*)(ws + 48 * MB);
  bf16* vt = (bf16*)(ws + 56 * MB);
  bf16* attnout = (bf16*)(ws + 64 * MB);
  float* x1 = (float*)qh;  // alias: qh/ql dead after attn
  bf16* h2 = (bf16*)(ws + 72 * MB);
  bf16* ff = kh;  // alias: kh/kl/vt/attnout dead after k4
  float* outp = (float*)d_out;

  // 0) attention-path weights f32 -> bf16 (exact for ternary)
  cvt4<<<4096, 256, 0, stream>>>(Wq, Wk, Wv, Wo, Wq_b);
  // 1) LN1 -> split bf16 hi/lo
  ln_kernel<true><<<4096, 256, 0, stream>>>(x, g1, b1, h_hi, h_lo);
  // 2) Q,K (split bf16, q pre-scaled 1/8) and V^T (bf16)
  gemm_qk<<<dim3(16, 32), 256, 0, stream>>>(h_hi, h_lo, Wq_b, Wk_b, qh, ql, kh,
                                            kl);
  gemm_v<<<dim3(8, 32), 256, 0, stream>>>(h_hi, h_lo, Wv_b, vt);
  // 2.5) h is dead now: convert FF weights into its slot
  cvt2<<<8192, 256, 0, stream>>>(Wf1, Wf2, Wf1_b);
  // 3) MFMA causal flash attention -> bf16 (B,T,1024)
  attn_kernel<<<1024, 256, 0, stream>>>(qh, ql, kh, kl, vt, attnout);
  // 4) x1 = x + attnout @ Wo^T   (f32; overwrites dead qh/ql)
  gemm_bt<2, false><<<dim3(8, 32), 256, 0, stream>>>(
      attnout, nullptr, Wo_b, (void*)x1, x, 4096, 1024, 1024);
  // 5) LN2 -> h2 (bf16)
  ln_kernel<false><<<4096, 256, 0, stream>>>(x1, g2, b2, h2, nullptr);
  // 6) ff = gelu(h2 @ Wff1^T)  (bf16; overwrites dead kh/kl/vt/attnout)
  gemm_bt<3, false><<<dim3(32, 32), 256, 0, stream>>>(
      h2, nullptr, Wf1_b, (void*)ff, nullptr, 4096, 4096, 1024);
  // 7) out = x1 + ff @ Wff2^T  (f32)
  gemm_bt<2, false><<<dim3(8, 32), 256, 0, stream>>>(
      ff, nullptr, Wf2_b, (void*)outp, x1, 4096, 1024, 4096);
}

// Round 5
// 488.388 us; speedup vs baseline: 2.1798x; 1.0186x over previous
//
#include <hip/hip_runtime.h>

typedef __bf16 bf16;
typedef bf16 bf16x8 __attribute__((ext_vector_type(8)));
typedef bf16 bf16x4 __attribute__((ext_vector_type(4)));
typedef float f32x4 __attribute__((ext_vector_type(4)));

// ---------------------------------------------------------------------------
// async global->LDS 16B copy (wave-uniform LDS base + lane*16 placement)
// ---------------------------------------------------------------------------
static __device__ __forceinline__ void async16(const void* g, void* l) {
  __builtin_amdgcn_global_load_lds((__attribute__((address_space(1))) void*)g,
                                   (__attribute__((address_space(3))) void*)l,
                                   16, 0, 0);
}

// ---------------------------------------------------------------------------
// Weight f32 -> bf16 conversion (ternary {-1,0,1}: exact in bf16).
// cvt4: Wq|Wk|Wv|Wo (1M el each) -> dst[0..4M).  grid 4096.
// cvt2: Wf1|Wf2   (4M el each)  -> dst[0..8M).  grid 8192 (runs after h dies).
// ---------------------------------------------------------------------------
__global__ __launch_bounds__(256) void cvt4(const float* __restrict__ a,
                                            const float* __restrict__ b,
                                            const float* __restrict__ c,
                                            const float* __restrict__ d,
                                            bf16* __restrict__ dst) {
  const size_t i = ((size_t)blockIdx.x * 256 + threadIdx.x) * 4;
  const size_t M1 = 1u << 20;
  const float* src = (i < M1) ? a : (i < 2 * M1) ? b : (i < 3 * M1) ? c : d;
  const size_t off = i & (M1 - 1);
  const float4 v = *(const float4*)(src + off);
  bf16x4 o = {(bf16)v.x, (bf16)v.y, (bf16)v.z, (bf16)v.w};
  *(bf16x4*)(dst + i) = o;
}

__global__ __launch_bounds__(256) void cvt2(const float* __restrict__ a,
                                            const float* __restrict__ b,
                                            bf16* __restrict__ dst) {
  const size_t i = ((size_t)blockIdx.x * 256 + threadIdx.x) * 4;
  const size_t M4 = 4u << 20;
  const float* src = (i < M4) ? a : b;
  const size_t off = (i < M4) ? i : i - M4;
  const float4 v = *(const float4*)(src + off);
  bf16x4 o = {(bf16)v.x, (bf16)v.y, (bf16)v.z, (bf16)v.w};
  *(bf16x4*)(dst + i) = o;
}

// ---------------------------------------------------------------------------
// GEMM: C[M,N] = A[M,K] * B[N,K]^T  (+ optional second A accumulated, epilogue)
// EPI: 0 = f32 store, 2 = f32(acc + R[f32]), 3 = bf16 gelu(acc),
//      4 = split bf16 hi/lo of (acc*scale)  (Cv=hi, C2=lo),
//      5 = bf16 store transposed to V^T global layout (b,h,d,t)
// 128x128 tile, BK=32, 256 threads = 4 waves (2x2 of 64x64), mfma 16x16x32 bf16
// ---------------------------------------------------------------------------
template <int EPI, bool SPLIT>
static __device__ __forceinline__ void gemm_body(
    const bf16* __restrict__ A, const bf16* __restrict__ A2,
    const bf16* __restrict__ B, void* __restrict__ Cv, void* __restrict__ C2,
    const float* __restrict__ R, float scale, int col0, int row0, int M, int N,
    int K) {
  __shared__ bf16 sA[128 * 32];
  __shared__ bf16 sB[128 * 32];
  const int tid = threadIdx.x;
  const int lane = tid & 63;
  const int wid = tid >> 6;
  const int wm = wid >> 1, wn = wid & 1;

  f32x4 acc[4][4];
  const f32x4 fzero = {0.f, 0.f, 0.f, 0.f};
#pragma unroll
  for (int i = 0; i < 4; ++i)
#pragma unroll
    for (int j = 0; j < 4; ++j) acc[i][j] = fzero;

  const int nk = K >> 5;
  const int total = SPLIT ? (nk << 1) : nk;
  const int r0 = tid >> 2, c0 = (tid & 3) << 3;
  const int r1 = (256 + tid) >> 2, c1 = ((256 + tid) & 3) << 3;
  bf16* lA0 = sA + (wid << 6) * 8;  // wave-uniform LDS bases
  bf16* lA1 = sA + (256 + (wid << 6)) * 8;
  bf16* lB0 = sB + (wid << 6) * 8;
  bf16* lB1 = sB + (256 + (wid << 6)) * 8;

  for (int kt = 0; kt < total; ++kt) {
    const int kk = (kt < nk) ? kt : kt - nk;
    const bf16* Ap = (SPLIT && kt >= nk) ? A2 : A;
    const int k0 = kk << 5;
    async16(Ap + (size_t)(row0 + r0) * K + k0 + c0, lA0);
    async16(Ap + (size_t)(row0 + r1) * K + k0 + c1, lA1);
    async16(B + (size_t)(col0 + r0) * K + k0 + c0, lB0);
    async16(B + (size_t)(col0 + r1) * K + k0 + c1, lB1);
    __syncthreads();
    const int fr = lane & 15, fq = (lane >> 4) << 3;
    bf16x8 af[4], bfr[4];
#pragma unroll
    for (int i = 0; i < 4; ++i)
      af[i] = *(const bf16x8*)&sA[(wm * 64 + i * 16 + fr) * 32 + fq];
#pragma unroll
    for (int j = 0; j < 4; ++j)
      bfr[j] = *(const bf16x8*)&sB[(wn * 64 + j * 16 + fr) * 32 + fq];
#pragma unroll
    for (int i = 0; i < 4; ++i)
#pragma unroll
      for (int j = 0; j < 4; ++j)
        acc[i][j] = __builtin_amdgcn_mfma_f32_16x16x32_bf16(af[i], bfr[j],
                                                            acc[i][j], 0, 0, 0);
    __syncthreads();
  }

  // C/D layout (m89-verified): col = lane&15, row = (lane>>4)*4 + reg
  const int fr = lane & 15, fq4 = (lane >> 4) << 2;
#pragma unroll
  for (int i = 0; i < 4; ++i) {
#pragma unroll
    for (int j = 0; j < 4; ++j) {
      const int rbase = row0 + wm * 64 + i * 16 + fq4;
      const int col = col0 + wn * 64 + j * 16 + fr;
      if constexpr (EPI == 5) {
        // V^T global: (b, h, d, t); rows rbase..rbase+3 are consecutive t
        const int b = rbase >> 11, t = rbase & 2047;
        const int hh = col >> 6, d = col & 63;
        bf16x4 o4 = {(bf16)acc[i][j][0], (bf16)acc[i][j][1],
                     (bf16)acc[i][j][2], (bf16)acc[i][j][3]};
        *(bf16x4*)&((bf16*)Cv)[(((size_t)(b * 16 + hh)) * 64 + d) * 2048 + t] =
            o4;
      } else {
#pragma unroll
        for (int r = 0; r < 4; ++r) {
          const size_t idx = (size_t)(rbase + r) * N + col;
          const float val = acc[i][j][r];
          if constexpr (EPI == 0) {
            ((float*)Cv)[idx] = val;
          } else if constexpr (EPI == 2) {
            ((float*)Cv)[idx] = val + R[idx];
          } else if constexpr (EPI == 3) {
            ((bf16*)Cv)[idx] =
                (bf16)(0.5f * val * (1.0f + erff(val * 0.7071067811865476f)));
          } else {  // EPI == 4: split hi/lo bf16 of val*scale
            const float vs = val * scale;
            const bf16 hi = (bf16)vs;
            ((bf16*)Cv)[idx] = hi;
            ((bf16*)C2)[idx] = (bf16)(vs - (float)hi);
          }
        }
      }
    }
  }
}

template <int EPI, bool SPLIT>
__global__ __launch_bounds__(256) void gemm_bt(
    const bf16* __restrict__ A, const bf16* __restrict__ A2,
    const bf16* __restrict__ B, void* __restrict__ Cv,
    const float* __restrict__ R, int M, int N, int K) {
  gemm_body<EPI, SPLIT>(A, A2, B, Cv, nullptr, R, 1.0f, blockIdx.x * 128,
                        blockIdx.y * 128, M, N, K);
}

// Q,K,V fused: grid (24, 32). bx>>3: 0=q (split, scaled 1/8), 1=k (split),
// 2=v (single-pass bf16 h, transposed store).
__global__ __launch_bounds__(256) void gemm_qkv(
    const bf16* __restrict__ A, const bf16* __restrict__ A2,
    const bf16* __restrict__ Bq, const bf16* __restrict__ Bk,
    const bf16* __restrict__ Bv, bf16* qh, bf16* ql, bf16* kh, bf16* kl,
    bf16* vt) {
  const int which = blockIdx.x >> 3;
  const int col0 = (blockIdx.x & 7) * 128, row0 = blockIdx.y * 128;
  if (which == 2) {
    gemm_body<5, false>(A, nullptr, Bv, (void*)vt, nullptr, nullptr, 1.0f,
                        col0, row0, 4096, 1024, 1024);
  } else {
    gemm_body<4, true>(A, A2, which ? Bk : Bq, which ? (void*)kh : (void*)qh,
                       which ? (void*)kl : (void*)ql, nullptr,
                       which ? 1.0f : 0.125f, col0, row0, 4096, 1024, 1024);
  }
}

// ---------------------------------------------------------------------------
// LayerNorm over D=1024 (f32 input), one block per row.
// ---------------------------------------------------------------------------
template <bool SPLIT>
__global__ __launch_bounds__(256) void ln_kernel(
    const float* __restrict__ x, const float* __restrict__ g,
    const float* __restrict__ b, bf16* __restrict__ hi, bf16* __restrict__ lo) {
  const int row = blockIdx.x;
  const int tid = threadIdx.x;
  const float* xr = x + (size_t)row * 1024;
  float v[4];
  float s1 = 0.f, s2 = 0.f;
#pragma unroll
  for (int j = 0; j < 4; ++j) {
    v[j] = xr[j * 256 + tid];
    s1 += v[j];
    s2 += v[j] * v[j];
  }
#pragma unroll
  for (int off = 1; off < 64; off <<= 1) {
    s1 += __shfl_xor(s1, off);
    s2 += __shfl_xor(s2, off);
  }
  __shared__ float ws1[4], ws2[4];
  const int wid = tid >> 6;
  if ((tid & 63) == 0) {
    ws1[wid] = s1;
    ws2[wid] = s2;
  }
  __syncthreads();
  s1 = ws1[0] + ws1[1] + ws1[2] + ws1[3];
  s2 = ws2[0] + ws2[1] + ws2[2] + ws2[3];
  const float mu = s1 * (1.f / 1024.f);
  const float var = s2 * (1.f / 1024.f) - mu * mu;
  const float rstd = 1.0f / sqrtf(var + 1e-5f);
#pragma unroll
  for (int j = 0; j < 4; ++j) {
    const int cc = j * 256 + tid;
    const float y = (v[j] - mu) * rstd * g[cc] + b[cc];
    const bf16 yh = (bf16)y;
    hi[(size_t)row * 1024 + cc] = yh;
    if constexpr (SPLIT) lo[(size_t)row * 1024 + cc] = (bf16)(y - (float)yh);
  }
}

// ---------------------------------------------------------------------------
// MFMA causal flash attention. Block = 256 thr = 4 waves = one (b,h,64-query
// tile); wave w owns queries [w*16, w*16+16).  Split-bf16 Q,K:
// S = qh*kh + qh*kl + ql*kh (lo*lo term ~3e-3, below logit-error budget).
// Q fragments hoisted into registers once (Q LDS region then reused for P at
// stride 76 -> conflict-free P writes: quad*152/4 mod 32 = {0,24,16,8}).
// Softmax f32 in registers (C-layout), PV in MFMA against V^T tile.
// LDS 46080 B -> 3 blocks/CU.  Long blocks (qt=31) launched first.
// ---------------------------------------------------------------------------
__global__ __launch_bounds__(256) void attn_kernel(
    const bf16* __restrict__ qh_g, const bf16* __restrict__ ql_g,
    const bf16* __restrict__ kh_g, const bf16* __restrict__ kl_g,
    const bf16* __restrict__ vt_g, bf16* __restrict__ out) {
  __shared__ bf16 lds[23040];  // 46080 B
  bf16* Qh = lds;              // 64 x 72 (dead after frag hoist)
  bf16* Ql = lds + 4608;       // 64 x 72 (dead after frag hoist)
  bf16* Kh = lds + 9216;       // 64 x 72
  bf16* Kl = lds + 13824;      // 64 x 72
  bf16* Vt = lds + 18432;      // 64 x 72, rows = dim d, cols = key
  bf16* Ps = lds;              // P tile, stride 76, in dead Q region

  const int bid = blockIdx.x;
  const int qt = 31 - (bid >> 5);  // long blocks first
  const int h = bid & 15;
  const int b = (bid >> 4) & 1;
  const int t0 = qt << 6;
  const int tid = threadIdx.x;
  const int w = tid >> 6;
  const int lane = tid & 63;
  const int c = lane & 15;
  const int quad = lane >> 4;

  // staging map: chunk idx -> (row idx>>3, col8 (idx&7)*8)
  const int r0 = tid >> 3, c0 = (tid & 7) << 3;
  const int r1 = (tid + 256) >> 3, c1 = ((tid + 256) & 7) << 3;

  const size_t qbase = ((size_t)(b * 2048 + t0)) * 1024 + h * 64;
  *(bf16x8*)&Qh[r0 * 72 + c0] = *(const bf16x8*)&qh_g[qbase + (size_t)r0 * 1024 + c0];
  *(bf16x8*)&Qh[r1 * 72 + c1] = *(const bf16x8*)&qh_g[qbase + (size_t)r1 * 1024 + c1];
  *(bf16x8*)&Ql[r0 * 72 + c0] = *(const bf16x8*)&ql_g[qbase + (size_t)r0 * 1024 + c0];
  *(bf16x8*)&Ql[r1 * 72 + c1] = *(const bf16x8*)&ql_g[qbase + (size_t)r1 * 1024 + c1];
  __syncthreads();  // Q staged -> hoist fragments into registers
  const int mrow = (w * 16 + c) * 72;
  bf16x8 aqh[2], aql[2];
#pragma unroll
  for (int s = 0; s < 2; ++s) {
    aqh[s] = *(const bf16x8*)&Qh[mrow + s * 32 + quad * 8];
    aql[s] = *(const bf16x8*)&Ql[mrow + s * 32 + quad * 8];
  }

  f32x4 o[4];
  const f32x4 fzero = {0.f, 0.f, 0.f, 0.f};
#pragma unroll
  for (int j = 0; j < 4; ++j) o[j] = fzero;
  float m_i[4] = {-3e38f, -3e38f, -3e38f, -3e38f};
  float l_i[4] = {0.f, 0.f, 0.f, 0.f};

  const size_t vtb = ((size_t)(b * 16 + h)) * 64 * 2048;  // + d*2048 + t

  for (int kt = 0; kt <= qt; ++kt) {
    const int kb = kt << 6;
    __syncthreads();  // (A) prev tile's frag/P reads complete before restage
    const size_t kbase = ((size_t)(b * 2048 + kb)) * 1024 + h * 64;
    *(bf16x8*)&Kh[r0 * 72 + c0] = *(const bf16x8*)&kh_g[kbase + (size_t)r0 * 1024 + c0];
    *(bf16x8*)&Kh[r1 * 72 + c1] = *(const bf16x8*)&kh_g[kbase + (size_t)r1 * 1024 + c1];
    *(bf16x8*)&Kl[r0 * 72 + c0] = *(const bf16x8*)&kl_g[kbase + (size_t)r0 * 1024 + c0];
    *(bf16x8*)&Kl[r1 * 72 + c1] = *(const bf16x8*)&kl_g[kbase + (size_t)r1 * 1024 + c1];
    *(bf16x8*)&Vt[r0 * 72 + c0] = *(const bf16x8*)&vt_g[vtb + (size_t)r0 * 2048 + kb + c0];
    *(bf16x8*)&Vt[r1 * 72 + c1] = *(const bf16x8*)&vt_g[vtb + (size_t)r1 * 2048 + kb + c1];
    __syncthreads();  // (B) staging visible

    bf16x8 bkh[4][2], bkl[4][2];
#pragma unroll
    for (int j = 0; j < 4; ++j)
#pragma unroll
      for (int s = 0; s < 2; ++s) {
        bkh[j][s] = *(const bf16x8*)&Kh[(j * 16 + c) * 72 + s * 32 + quad * 8];
        bkl[j][s] = *(const bf16x8*)&Kl[(j * 16 + c) * 72 + s * 32 + quad * 8];
      }

    f32x4 s4[4];
#pragma unroll
    for (int j = 0; j < 4; ++j) s4[j] = fzero;
#pragma unroll
    for (int j = 0; j < 4; ++j)
#pragma unroll
      for (int s = 0; s < 2; ++s) {
        s4[j] = __builtin_amdgcn_mfma_f32_16x16x32_bf16(aqh[s], bkh[j][s], s4[j], 0, 0, 0);
        s4[j] = __builtin_amdgcn_mfma_f32_16x16x32_bf16(aqh[s], bkl[j][s], s4[j], 0, 0, 0);
        s4[j] = __builtin_amdgcn_mfma_f32_16x16x32_bf16(aql[s], bkh[j][s], s4[j], 0, 0, 0);
      }

    if (kt == qt) {  // diagonal tile: strict-upper mask (t0 == kb)
#pragma unroll
      for (int j = 0; j < 4; ++j)
#pragma unroll
        for (int r = 0; r < 4; ++r)
          if (j * 16 + c > w * 16 + quad * 4 + r) s4[j][r] = -3e38f;
    }

    float al[4], p[4][4];
#pragma unroll
    for (int r = 0; r < 4; ++r) {
      float mt = fmaxf(fmaxf(s4[0][r], s4[1][r]), fmaxf(s4[2][r], s4[3][r]));
#pragma unroll
      for (int off = 1; off < 16; off <<= 1) mt = fmaxf(mt, __shfl_xor(mt, off));
      const float mn = fmaxf(m_i[r], mt);
      al[r] = __expf(m_i[r] - mn);
      float ps = 0.f;
#pragma unroll
      for (int j = 0; j < 4; ++j) {
        p[r][j] = __expf(s4[j][r] - mn);
        ps += p[r][j];
      }
#pragma unroll
      for (int off = 1; off < 16; off <<= 1) ps += __shfl_xor(ps, off);
      l_i[r] = l_i[r] * al[r] + ps;
      m_i[r] = mn;
#pragma unroll
      for (int j = 0; j < 4; ++j) o[j][r] *= al[r];
    }

    // P -> dead Q region, stride 76 (conflict-free writes)
    bf16* Pw = Ps + w * 16 * 76;
#pragma unroll
    for (int r = 0; r < 4; ++r)
#pragma unroll
      for (int j = 0; j < 4; ++j)
        Pw[(quad * 4 + r) * 76 + j * 16 + c] = (bf16)p[r][j];

    __syncthreads();  // (D) P stores committed before fragment reads

    bf16x8 ap[2], bv[4][2];
#pragma unroll
    for (int s = 0; s < 2; ++s)
      ap[s] = *(const bf16x8*)&Pw[c * 76 + s * 32 + quad * 8];
#pragma unroll
    for (int j = 0; j < 4; ++j)
#pragma unroll
      for (int s = 0; s < 2; ++s)
        bv[j][s] = *(const bf16x8*)&Vt[(j * 16 + c) * 72 + s * 32 + quad * 8];
#pragma unroll
    for (int j = 0; j < 4; ++j)
#pragma unroll
      for (int s = 0; s < 2; ++s)
        o[j] = __builtin_amdgcn_mfma_f32_16x16x32_bf16(ap[s], bv[j][s], o[j], 0, 0, 0);
  }

#pragma unroll
  for (int r = 0; r < 4; ++r) {
    const float inv = 1.0f / l_i[r];
#pragma unroll
    for (int j = 0; j < 4; ++j) {
      const size_t oi =
          ((size_t)(b * 2048 + t0 + w * 16 + quad * 4 + r)) * 1024 + h * 64 +
          j * 16 + c;
      out[oi] = (bf16)(o[j][r] * inv);
    }
  }
}

// ---------------------------------------------------------------------------
// Workspace plan (80 MiB peak; >104 MiB previously corrupted harness memory):
//   [ 0, 8)   Wq|Wk|Wv|Wo bf16
//   [ 8,24)   h_hi|h_lo  -> (after gemm_qkv) Wf1_b|Wf2_b   (cvt2 overwrite)
//   [24,40)   qh|ql      -> (after attn)   x1 (f32)
//   [40,72)   kh|kl|vt|attnout -> (after k4) ff (bf16 4096x4096)
//   [72,80)   h2
// ---------------------------------------------------------------------------
extern "C" void kernel_launch(void* const* d_in, const int* in_sizes, int n_in,
                              void* d_out, int out_size, void* d_ws,
                              size_t ws_size, hipStream_t stream) {
  const float* x = (const float*)d_in[0];
  const float* g1 = (const float*)d_in[2];
  const float* b1 = (const float*)d_in[3];
  const float* g2 = (const float*)d_in[4];
  const float* b2 = (const float*)d_in[5];
  const float* Wq = (const float*)d_in[6];
  const float* Wk = (const float*)d_in[7];
  const float* Wv = (const float*)d_in[8];
  const float* Wo = (const float*)d_in[9];
  const float* Wf1 = (const float*)d_in[10];
  const float* Wf2 = (const float*)d_in[11];
  char* ws = (char*)d_ws;
  const size_t MB = 1024 * 1024;
  const size_t M1 = 1u << 20;
  bf16* Wq_b = (bf16*)ws;
  bf16* Wk_b = Wq_b + 1 * M1;
  bf16* Wv_b = Wq_b + 2 * M1;
  bf16* Wo_b = Wq_b + 3 * M1;
  bf16* h_hi = (bf16*)(ws + 8 * MB);
  bf16* h_lo = (bf16*)(ws + 16 * MB);
  bf16* Wf1_b = h_hi;  // alias: h dead after gemm_qkv; cvt2 fills before k6
  bf16* Wf2_b = h_lo;
  bf16* qh = (bf16*)(ws + 24 * MB);
  bf16* ql = (bf16*)(ws + 32 * MB);
  bf16* kh = (bf16*)(ws + 40 * MB);
  bf16* kl = (bf16*)(ws + 48 * MB);
  bf16* vt = (bf16*)(ws + 56 * MB);
  bf16* attnout = (bf16*)(ws + 64 * MB);
  float* x1 = (float*)qh;  // alias: qh/ql dead after attn
  bf16* h2 = (bf16*)(ws + 72 * MB);
  bf16* ff = kh;  // alias: kh/kl/vt/attnout dead after k4
  float* outp = (float*)d_out;

  // 0) attention-path weights f32 -> bf16 (exact for ternary)
  cvt4<<<4096, 256, 0, stream>>>(Wq, Wk, Wv, Wo, Wq_b);
  // 1) LN1 -> split bf16 hi/lo
  ln_kernel<true><<<4096, 256, 0, stream>>>(x, g1, b1, h_hi, h_lo);
  // 2) Q,K (split bf16, q pre-scaled 1/8) + V^T (single-pass bf16) fused
  gemm_qkv<<<dim3(24, 32), 256, 0, stream>>>(h_hi, h_lo, Wq_b, Wk_b, Wv_b, qh,
                                             ql, kh, kl, vt);
  // 2.5) h is dead now: convert FF weights into its slot
  cvt2<<<8192, 256, 0, stream>>>(Wf1, Wf2, Wf1_b);
  // 3) MFMA causal flash attention -> bf16 (B,T,1024)
  attn_kernel<<<1024, 256, 0, stream>>>(qh, ql, kh, kl, vt, attnout);
  // 4) x1 = x + attnout @ Wo^T   (f32; overwrites dead qh/ql)
  gemm_bt<2, false><<<dim3(8, 32), 256, 0, stream>>>(
      attnout, nullptr, Wo_b, (void*)x1, x, 4096, 1024, 1024);
  // 5) LN2 -> h2 (bf16)
  ln_kernel<false><<<4096, 256, 0, stream>>>(x1, g2, b2, h2, nullptr);
  // 6) ff = gelu(h2 @ Wff1^T)  (bf16; overwrites dead kh/kl/vt/attnout)
  gemm_bt<3, false><<<dim3(32, 32), 256, 0, stream>>>(
      h2, nullptr, Wf1_b, (void*)ff, nullptr, 4096, 4096, 1024);
  // 7) out = x1 + ff @ Wff2^T  (f32)
  gemm_bt<2, false><<<dim3(8, 32), 256, 0, stream>>>(
      ff, nullptr, Wf2_b, (void*)outp, x1, 4096, 1024, 4096);
}

// Round 6
// 475.341 us; speedup vs baseline: 2.2396x; 1.0274x over previous
//
#include <hip/hip_runtime.h>

typedef __bf16 bf16;
typedef bf16 bf16x8 __attribute__((ext_vector_type(8)));
typedef bf16 bf16x4 __attribute__((ext_vector_type(4)));
typedef float f32x4 __attribute__((ext_vector_type(4)));

// ---------------------------------------------------------------------------
// async global->LDS 16B copy (wave-uniform LDS base + lane*16 placement)
// ---------------------------------------------------------------------------
static __device__ __forceinline__ void async16(const void* g, void* l) {
  __builtin_amdgcn_global_load_lds((__attribute__((address_space(1))) void*)g,
                                   (__attribute__((address_space(3))) void*)l,
                                   16, 0, 0);
}

// ---------------------------------------------------------------------------
// Weight f32 -> bf16 conversion (ternary {-1,0,1}: exact in bf16).
// ---------------------------------------------------------------------------
__global__ __launch_bounds__(256) void cvt4(const float* __restrict__ a,
                                            const float* __restrict__ b,
                                            const float* __restrict__ c,
                                            const float* __restrict__ d,
                                            bf16* __restrict__ dst) {
  const size_t i = ((size_t)blockIdx.x * 256 + threadIdx.x) * 4;
  const size_t M1 = 1u << 20;
  const float* src = (i < M1) ? a : (i < 2 * M1) ? b : (i < 3 * M1) ? c : d;
  const size_t off = i & (M1 - 1);
  const float4 v = *(const float4*)(src + off);
  bf16x4 o = {(bf16)v.x, (bf16)v.y, (bf16)v.z, (bf16)v.w};
  *(bf16x4*)(dst + i) = o;
}

__global__ __launch_bounds__(256) void cvt2(const float* __restrict__ a,
                                            const float* __restrict__ b,
                                            bf16* __restrict__ dst) {
  const size_t i = ((size_t)blockIdx.x * 256 + threadIdx.x) * 4;
  const size_t M4 = 4u << 20;
  const float* src = (i < M4) ? a : b;
  const size_t off = (i < M4) ? i : i - M4;
  const float4 v = *(const float4*)(src + off);
  bf16x4 o = {(bf16)v.x, (bf16)v.y, (bf16)v.z, (bf16)v.w};
  *(bf16x4*)(dst + i) = o;
}

// ---------------------------------------------------------------------------
// GEMM: C[M,N] = A[M,K] * B[N,K]^T  (+ optional second A accumulated, epilogue)
// EPI: 0 = f32 store, 2 = f32(acc + R[f32]), 3 = bf16 gelu(acc),
//      4 = split bf16 hi/lo of (acc*scale)  (Cv=hi, C2=lo),
//      5 = bf16 store transposed to V^T global layout (b,h,d,t)
// 128x128 tile, BK=32, 256 threads = 4 waves (2x2 of 64x64), mfma 16x16x32 bf16
// ---------------------------------------------------------------------------
template <int EPI, bool SPLIT>
static __device__ __forceinline__ void gemm_body(
    const bf16* __restrict__ A, const bf16* __restrict__ A2,
    const bf16* __restrict__ B, void* __restrict__ Cv, void* __restrict__ C2,
    const float* __restrict__ R, float scale, int col0, int row0, int M, int N,
    int K) {
  __shared__ bf16 sA[128 * 32];
  __shared__ bf16 sB[128 * 32];
  const int tid = threadIdx.x;
  const int lane = tid & 63;
  const int wid = tid >> 6;
  const int wm = wid >> 1, wn = wid & 1;

  f32x4 acc[4][4];
  const f32x4 fzero = {0.f, 0.f, 0.f, 0.f};
#pragma unroll
  for (int i = 0; i < 4; ++i)
#pragma unroll
    for (int j = 0; j < 4; ++j) acc[i][j] = fzero;

  const int nk = K >> 5;
  const int total = SPLIT ? (nk << 1) : nk;
  const int r0 = tid >> 2, c0 = (tid & 3) << 3;
  const int r1 = (256 + tid) >> 2, c1 = ((256 + tid) & 3) << 3;
  bf16* lA0 = sA + (wid << 6) * 8;  // wave-uniform LDS bases
  bf16* lA1 = sA + (256 + (wid << 6)) * 8;
  bf16* lB0 = sB + (wid << 6) * 8;
  bf16* lB1 = sB + (256 + (wid << 6)) * 8;

  for (int kt = 0; kt < total; ++kt) {
    const int kk = (kt < nk) ? kt : kt - nk;
    const bf16* Ap = (SPLIT && kt >= nk) ? A2 : A;
    const int k0 = kk << 5;
    async16(Ap + (size_t)(row0 + r0) * K + k0 + c0, lA0);
    async16(Ap + (size_t)(row0 + r1) * K + k0 + c1, lA1);
    async16(B + (size_t)(col0 + r0) * K + k0 + c0, lB0);
    async16(B + (size_t)(col0 + r1) * K + k0 + c1, lB1);
    __syncthreads();
    const int fr = lane & 15, fq = (lane >> 4) << 3;
    bf16x8 af[4], bfr[4];
#pragma unroll
    for (int i = 0; i < 4; ++i)
      af[i] = *(const bf16x8*)&sA[(wm * 64 + i * 16 + fr) * 32 + fq];
#pragma unroll
    for (int j = 0; j < 4; ++j)
      bfr[j] = *(const bf16x8*)&sB[(wn * 64 + j * 16 + fr) * 32 + fq];
#pragma unroll
    for (int i = 0; i < 4; ++i)
#pragma unroll
      for (int j = 0; j < 4; ++j)
        acc[i][j] = __builtin_amdgcn_mfma_f32_16x16x32_bf16(af[i], bfr[j],
                                                            acc[i][j], 0, 0, 0);
    __syncthreads();
  }

  // C/D layout (m89-verified): col = lane&15, row = (lane>>4)*4 + reg
  const int fr = lane & 15, fq4 = (lane >> 4) << 2;
#pragma unroll
  for (int i = 0; i < 4; ++i) {
#pragma unroll
    for (int j = 0; j < 4; ++j) {
      const int rbase = row0 + wm * 64 + i * 16 + fq4;
      const int col = col0 + wn * 64 + j * 16 + fr;
      if constexpr (EPI == 5) {
        // V^T global: (b, h, d, t); rows rbase..rbase+3 are consecutive t
        const int b = rbase >> 11, t = rbase & 2047;
        const int hh = col >> 6, d = col & 63;
        bf16x4 o4 = {(bf16)acc[i][j][0], (bf16)acc[i][j][1],
                     (bf16)acc[i][j][2], (bf16)acc[i][j][3]};
        *(bf16x4*)&((bf16*)Cv)[(((size_t)(b * 16 + hh)) * 64 + d) * 2048 + t] =
            o4;
      } else {
#pragma unroll
        for (int r = 0; r < 4; ++r) {
          const size_t idx = (size_t)(rbase + r) * N + col;
          const float val = acc[i][j][r];
          if constexpr (EPI == 0) {
            ((float*)Cv)[idx] = val;
          } else if constexpr (EPI == 2) {
            ((float*)Cv)[idx] = val + R[idx];
          } else if constexpr (EPI == 3) {
            ((bf16*)Cv)[idx] =
                (bf16)(0.5f * val * (1.0f + erff(val * 0.7071067811865476f)));
          } else {  // EPI == 4: split hi/lo bf16 of val*scale
            const float vs = val * scale;
            const bf16 hi = (bf16)vs;
            ((bf16*)Cv)[idx] = hi;
            ((bf16*)C2)[idx] = (bf16)(vs - (float)hi);
          }
        }
      }
    }
  }
}

template <int EPI, bool SPLIT>
__global__ __launch_bounds__(256) void gemm_bt(
    const bf16* __restrict__ A, const bf16* __restrict__ A2,
    const bf16* __restrict__ B, void* __restrict__ Cv,
    const float* __restrict__ R, int M, int N, int K) {
  gemm_body<EPI, SPLIT>(A, A2, B, Cv, nullptr, R, 1.0f, blockIdx.x * 128,
                        blockIdx.y * 128, M, N, K);
}

// Q,K,V fused: grid (24, 32). bx>>3: 0=q (split, scaled 1/8), 1=k (split),
// 2=v (single-pass bf16 h, transposed store).
__global__ __launch_bounds__(256) void gemm_qkv(
    const bf16* __restrict__ A, const bf16* __restrict__ A2,
    const bf16* __restrict__ Bq, const bf16* __restrict__ Bk,
    const bf16* __restrict__ Bv, bf16* qh, bf16* ql, bf16* kh, bf16* kl,
    bf16* vt) {
  const int which = blockIdx.x >> 3;
  const int col0 = (blockIdx.x & 7) * 128, row0 = blockIdx.y * 128;
  if (which == 2) {
    gemm_body<5, false>(A, nullptr, Bv, (void*)vt, nullptr, nullptr, 1.0f,
                        col0, row0, 4096, 1024, 1024);
  } else {
    gemm_body<4, true>(A, A2, which ? Bk : Bq, which ? (void*)kh : (void*)qh,
                       which ? (void*)kl : (void*)ql, nullptr,
                       which ? 1.0f : 0.125f, col0, row0, 4096, 1024, 1024);
  }
}

// ---------------------------------------------------------------------------
// LayerNorm over D=1024 (f32 input), one block per row.
// ---------------------------------------------------------------------------
template <bool SPLIT>
__global__ __launch_bounds__(256) void ln_kernel(
    const float* __restrict__ x, const float* __restrict__ g,
    const float* __restrict__ b, bf16* __restrict__ hi, bf16* __restrict__ lo) {
  const int row = blockIdx.x;
  const int tid = threadIdx.x;
  const float* xr = x + (size_t)row * 1024;
  float v[4];
  float s1 = 0.f, s2 = 0.f;
#pragma unroll
  for (int j = 0; j < 4; ++j) {
    v[j] = xr[j * 256 + tid];
    s1 += v[j];
    s2 += v[j] * v[j];
  }
#pragma unroll
  for (int off = 1; off < 64; off <<= 1) {
    s1 += __shfl_xor(s1, off);
    s2 += __shfl_xor(s2, off);
  }
  __shared__ float ws1[4], ws2[4];
  const int wid = tid >> 6;
  if ((tid & 63) == 0) {
    ws1[wid] = s1;
    ws2[wid] = s2;
  }
  __syncthreads();
  s1 = ws1[0] + ws1[1] + ws1[2] + ws1[3];
  s2 = ws2[0] + ws2[1] + ws2[2] + ws2[3];
  const float mu = s1 * (1.f / 1024.f);
  const float var = s2 * (1.f / 1024.f) - mu * mu;
  const float rstd = 1.0f / sqrtf(var + 1e-5f);
#pragma unroll
  for (int j = 0; j < 4; ++j) {
    const int cc = j * 256 + tid;
    const float y = (v[j] - mu) * rstd * g[cc] + b[cc];
    const bf16 yh = (bf16)y;
    hi[(size_t)row * 1024 + cc] = yh;
    if constexpr (SPLIT) lo[(size_t)row * 1024 + cc] = (bf16)(y - (float)yh);
  }
}

// ---------------------------------------------------------------------------
// MFMA causal flash attention, latency-optimized.
//  - Q fragments loaded straight from global (no Q LDS region)
//  - next K/V tile prefetched into registers during current tile's compute
//  - 2 barriers/iter; P tile wave-private (own region, stride 76, no barrier)
//  - LDS 37376 B -> 4 blocks/CU (16 waves); __launch_bounds__(256,4)
// Split-bf16 Q,K: S = qh*kh + qh*kl + ql*kh (lo*lo ~3e-3, below budget).
// Long blocks (qt=31) launched first to beat causal imbalance.
// ---------------------------------------------------------------------------
__global__ __launch_bounds__(256, 4) void attn_kernel(
    const bf16* __restrict__ qh_g, const bf16* __restrict__ ql_g,
    const bf16* __restrict__ kh_g, const bf16* __restrict__ kl_g,
    const bf16* __restrict__ vt_g, bf16* __restrict__ out) {
  __shared__ bf16 lds[18688];  // 37376 B
  bf16* Kh = lds;              // 64 x 72
  bf16* Kl = lds + 4608;       // 64 x 72
  bf16* Vt = lds + 9216;       // 64 x 72, rows = dim d, cols = key
  bf16* Ps = lds + 13824;      // 64 x 76 (wave-private 16-row blocks)

  const int bid = blockIdx.x;
  const int qt = 31 - (bid >> 5);  // long blocks first
  const int h = bid & 15;
  const int b = (bid >> 4) & 1;
  const int t0 = qt << 6;
  const int tid = threadIdx.x;
  const int w = tid >> 6;
  const int lane = tid & 63;
  const int c = lane & 15;
  const int quad = lane >> 4;

  // staging map: chunk idx -> (row idx>>3, col8 (idx&7)*8)
  const int r0 = tid >> 3, c0 = (tid & 7) << 3;
  const int r1 = (tid + 256) >> 3, c1 = ((tid + 256) & 7) << 3;

  // Q fragments straight from global (once per block)
  const size_t qrow =
      ((size_t)(b * 2048 + t0 + w * 16 + c)) * 1024 + h * 64 + quad * 8;
  bf16x8 aqh[2], aql[2];
  aqh[0] = *(const bf16x8*)&qh_g[qrow];
  aqh[1] = *(const bf16x8*)&qh_g[qrow + 32];
  aql[0] = *(const bf16x8*)&ql_g[qrow];
  aql[1] = *(const bf16x8*)&ql_g[qrow + 32];

  f32x4 o[4];
  const f32x4 fzero = {0.f, 0.f, 0.f, 0.f};
#pragma unroll
  for (int j = 0; j < 4; ++j) o[j] = fzero;
  float m_i[4] = {-3e38f, -3e38f, -3e38f, -3e38f};
  float l_i[4] = {0.f, 0.f, 0.f, 0.f};

  const size_t vtb = ((size_t)(b * 16 + h)) * 64 * 2048;  // + d*2048 + t
  const size_t kband = ((size_t)(b * 2048)) * 1024 + h * 64;

  bf16x8 gk[6];  // register prefetch of next K/V tile
  {
    gk[0] = *(const bf16x8*)&kh_g[kband + (size_t)r0 * 1024 + c0];
    gk[1] = *(const bf16x8*)&kh_g[kband + (size_t)r1 * 1024 + c1];
    gk[2] = *(const bf16x8*)&kl_g[kband + (size_t)r0 * 1024 + c0];
    gk[3] = *(const bf16x8*)&kl_g[kband + (size_t)r1 * 1024 + c1];
    gk[4] = *(const bf16x8*)&vt_g[vtb + (size_t)r0 * 2048 + c0];
    gk[5] = *(const bf16x8*)&vt_g[vtb + (size_t)r1 * 2048 + c1];
  }

  for (int kt = 0; kt <= qt; ++kt) {
    __syncthreads();  // (A) prev tile's fragment reads done before restage
    *(bf16x8*)&Kh[r0 * 72 + c0] = gk[0];
    *(bf16x8*)&Kh[r1 * 72 + c1] = gk[1];
    *(bf16x8*)&Kl[r0 * 72 + c0] = gk[2];
    *(bf16x8*)&Kl[r1 * 72 + c1] = gk[3];
    *(bf16x8*)&Vt[r0 * 72 + c0] = gk[4];
    *(bf16x8*)&Vt[r1 * 72 + c1] = gk[5];
    __syncthreads();  // (B) staging visible

    if (kt < qt) {  // prefetch next tile; latency hidden behind compute
      const int kb1 = (kt + 1) << 6;
      const size_t kbase = kband + (size_t)kb1 * 1024;
      gk[0] = *(const bf16x8*)&kh_g[kbase + (size_t)r0 * 1024 + c0];
      gk[1] = *(const bf16x8*)&kh_g[kbase + (size_t)r1 * 1024 + c1];
      gk[2] = *(const bf16x8*)&kl_g[kbase + (size_t)r0 * 1024 + c0];
      gk[3] = *(const bf16x8*)&kl_g[kbase + (size_t)r1 * 1024 + c1];
      gk[4] = *(const bf16x8*)&vt_g[vtb + (size_t)r0 * 2048 + kb1 + c0];
      gk[5] = *(const bf16x8*)&vt_g[vtb + (size_t)r1 * 2048 + kb1 + c1];
    }

    bf16x8 bkh[4][2], bkl[4][2];
#pragma unroll
    for (int j = 0; j < 4; ++j)
#pragma unroll
      for (int s = 0; s < 2; ++s) {
        bkh[j][s] = *(const bf16x8*)&Kh[(j * 16 + c) * 72 + s * 32 + quad * 8];
        bkl[j][s] = *(const bf16x8*)&Kl[(j * 16 + c) * 72 + s * 32 + quad * 8];
      }

    f32x4 s4[4];
#pragma unroll
    for (int j = 0; j < 4; ++j) s4[j] = fzero;
#pragma unroll
    for (int j = 0; j < 4; ++j)
#pragma unroll
      for (int s = 0; s < 2; ++s) {
        s4[j] = __builtin_amdgcn_mfma_f32_16x16x32_bf16(aqh[s], bkh[j][s], s4[j], 0, 0, 0);
        s4[j] = __builtin_amdgcn_mfma_f32_16x16x32_bf16(aqh[s], bkl[j][s], s4[j], 0, 0, 0);
        s4[j] = __builtin_amdgcn_mfma_f32_16x16x32_bf16(aql[s], bkh[j][s], s4[j], 0, 0, 0);
      }

    if (kt == qt) {  // diagonal tile: strict-upper mask (t0 == kb)
#pragma unroll
      for (int j = 0; j < 4; ++j)
#pragma unroll
        for (int r = 0; r < 4; ++r)
          if (j * 16 + c > w * 16 + quad * 4 + r) s4[j][r] = -3e38f;
    }

    float al[4], p[4][4];
#pragma unroll
    for (int r = 0; r < 4; ++r) {
      float mt = fmaxf(fmaxf(s4[0][r], s4[1][r]), fmaxf(s4[2][r], s4[3][r]));
#pragma unroll
      for (int off = 1; off < 16; off <<= 1) mt = fmaxf(mt, __shfl_xor(mt, off));
      const float mn = fmaxf(m_i[r], mt);
      al[r] = __expf(m_i[r] - mn);
      float ps = 0.f;
#pragma unroll
      for (int j = 0; j < 4; ++j) {
        p[r][j] = __expf(s4[j][r] - mn);
        ps += p[r][j];
      }
#pragma unroll
      for (int off = 1; off < 16; off <<= 1) ps += __shfl_xor(ps, off);
      l_i[r] = l_i[r] * al[r] + ps;
      m_i[r] = mn;
#pragma unroll
      for (int j = 0; j < 4; ++j) o[j][r] *= al[r];
    }

    // P -> wave-private region, stride 76 (conflict-free; intra-wave RAW only)
    bf16* Pw = Ps + w * 16 * 76;
#pragma unroll
    for (int r = 0; r < 4; ++r)
#pragma unroll
      for (int j = 0; j < 4; ++j)
        Pw[(quad * 4 + r) * 76 + j * 16 + c] = (bf16)p[r][j];

    bf16x8 ap[2], bv[4][2];
#pragma unroll
    for (int s = 0; s < 2; ++s)
      ap[s] = *(const bf16x8*)&Pw[c * 76 + s * 32 + quad * 8];
#pragma unroll
    for (int j = 0; j < 4; ++j)
#pragma unroll
      for (int s = 0; s < 2; ++s)
        bv[j][s] = *(const bf16x8*)&Vt[(j * 16 + c) * 72 + s * 32 + quad * 8];
#pragma unroll
    for (int j = 0; j < 4; ++j)
#pragma unroll
      for (int s = 0; s < 2; ++s)
        o[j] = __builtin_amdgcn_mfma_f32_16x16x32_bf16(ap[s], bv[j][s], o[j], 0, 0, 0);
  }

#pragma unroll
  for (int r = 0; r < 4; ++r) {
    const float inv = 1.0f / l_i[r];
#pragma unroll
    for (int j = 0; j < 4; ++j) {
      const size_t oi =
          ((size_t)(b * 2048 + t0 + w * 16 + quad * 4 + r)) * 1024 + h * 64 +
          j * 16 + c;
      out[oi] = (bf16)(o[j][r] * inv);
    }
  }
}

// ---------------------------------------------------------------------------
// Workspace plan (80 MiB peak; >104 MiB previously corrupted harness memory):
//   [ 0, 8)   Wq|Wk|Wv|Wo bf16
//   [ 8,24)   h_hi|h_lo  -> (after gemm_qkv) Wf1_b|Wf2_b   (cvt2 overwrite)
//   [24,40)   qh|ql      -> (after attn)   x1 (f32)
//   [40,72)   kh|kl|vt|attnout -> (after k4) ff (bf16 4096x4096)
//   [72,80)   h2
// ---------------------------------------------------------------------------
extern "C" void kernel_launch(void* const* d_in, const int* in_sizes, int n_in,
                              void* d_out, int out_size, void* d_ws,
                              size_t ws_size, hipStream_t stream) {
  const float* x = (const float*)d_in[0];
  const float* g1 = (const float*)d_in[2];
  const float* b1 = (const float*)d_in[3];
  const float* g2 = (const float*)d_in[4];
  const float* b2 = (const float*)d_in[5];
  const float* Wq = (const float*)d_in[6];
  const float* Wk = (const float*)d_in[7];
  const float* Wv = (const float*)d_in[8];
  const float* Wo = (const float*)d_in[9];
  const float* Wf1 = (const float*)d_in[10];
  const float* Wf2 = (const float*)d_in[11];
  char* ws = (char*)d_ws;
  const size_t MB = 1024 * 1024;
  const size_t M1 = 1u << 20;
  bf16* Wq_b = (bf16*)ws;
  bf16* Wk_b = Wq_b + 1 * M1;
  bf16* Wv_b = Wq_b + 2 * M1;
  bf16* Wo_b = Wq_b + 3 * M1;
  bf16* h_hi = (bf16*)(ws + 8 * MB);
  bf16* h_lo = (bf16*)(ws + 16 * MB);
  bf16* Wf1_b = h_hi;  // alias: h dead after gemm_qkv; cvt2 fills before k6
  bf16* Wf2_b = h_lo;
  bf16* qh = (bf16*)(ws + 24 * MB);
  bf16* ql = (bf16*)(ws + 32 * MB);
  bf16* kh = (bf16*)(ws + 40 * MB);
  bf16* kl = (bf16*)(ws + 48 * MB);
  bf16* vt = (bf16*)(ws + 56 * MB);
  bf16* attnout = (bf16*)(ws + 64 * MB);
  float* x1 = (float*)qh;  // alias: qh/ql dead after attn
  bf16* h2 = (bf16*)(ws + 72 * MB);
  bf16* ff = kh;  // alias: kh/kl/vt/attnout dead after k4
  float* outp = (float*)d_out;

  // 0) attention-path weights f32 -> bf16 (exact for ternary)
  cvt4<<<4096, 256, 0, stream>>>(Wq, Wk, Wv, Wo, Wq_b);
  // 1) LN1 -> split bf16 hi/lo
  ln_kernel<true><<<4096, 256, 0, stream>>>(x, g1, b1, h_hi, h_lo);
  // 2) Q,K (split bf16, q pre-scaled 1/8) + V^T (single-pass bf16) fused
  gemm_qkv<<<dim3(24, 32), 256, 0, stream>>>(h_hi, h_lo, Wq_b, Wk_b, Wv_b, qh,
                                             ql, kh, kl, vt);
  // 2.5) h is dead now: convert FF weights into its slot
  cvt2<<<8192, 256, 0, stream>>>(Wf1, Wf2, Wf1_b);
  // 3) MFMA causal flash attention -> bf16 (B,T,1024)
  attn_kernel<<<1024, 256, 0, stream>>>(qh, ql, kh, kl, vt, attnout);
  // 4) x1 = x + attnout @ Wo^T   (f32; overwrites dead qh/ql)
  gemm_bt<2, false><<<dim3(8, 32), 256, 0, stream>>>(
      attnout, nullptr, Wo_b, (void*)x1, x, 4096, 1024, 1024);
  // 5) LN2 -> h2 (bf16)
  ln_kernel<false><<<4096, 256, 0, stream>>>(x1, g2, b2, h2, nullptr);
  // 6) ff = gelu(h2 @ Wff1^T)  (bf16; overwrites dead kh/kl/vt/attnout)
  gemm_bt<3, false><<<dim3(32, 32), 256, 0, stream>>>(
      h2, nullptr, Wf1_b, (void*)ff, nullptr, 4096, 4096, 1024);
  // 7) out = x1 + ff @ Wff2^T  (f32)
  gemm_bt<2, false><<<dim3(8, 32), 256, 0, stream>>>(
      ff, nullptr, Wf2_b, (void*)outp, x1, 4096, 1024, 4096);
}

// Round 7
// 470.628 us; speedup vs baseline: 2.2620x; 1.0100x over previous
//
#include <hip/hip_runtime.h>

typedef __bf16 bf16;
typedef bf16 bf16x8 __attribute__((ext_vector_type(8)));
typedef bf16 bf16x4 __attribute__((ext_vector_type(4)));
typedef float f32x4 __attribute__((ext_vector_type(4)));

// ---------------------------------------------------------------------------
// async global->LDS 16B copy (wave-uniform LDS base + lane*16 placement)
// ---------------------------------------------------------------------------
static __device__ __forceinline__ void async16(const void* g, void* l) {
  __builtin_amdgcn_global_load_lds((__attribute__((address_space(1))) void*)g,
                                   (__attribute__((address_space(3))) void*)l,
                                   16, 0, 0);
}

// ---------------------------------------------------------------------------
// Weight f32 -> bf16 conversion (ternary {-1,0,1}: exact in bf16).
// ---------------------------------------------------------------------------
__global__ __launch_bounds__(256) void cvt4(const float* __restrict__ a,
                                            const float* __restrict__ b,
                                            const float* __restrict__ c,
                                            const float* __restrict__ d,
                                            bf16* __restrict__ dst) {
  const size_t i = ((size_t)blockIdx.x * 256 + threadIdx.x) * 4;
  const size_t M1 = 1u << 20;
  const float* src = (i < M1) ? a : (i < 2 * M1) ? b : (i < 3 * M1) ? c : d;
  const size_t off = i & (M1 - 1);
  const float4 v = *(const float4*)(src + off);
  bf16x4 o = {(bf16)v.x, (bf16)v.y, (bf16)v.z, (bf16)v.w};
  *(bf16x4*)(dst + i) = o;
}

__global__ __launch_bounds__(256) void cvt2(const float* __restrict__ a,
                                            const float* __restrict__ b,
                                            bf16* __restrict__ dst) {
  const size_t i = ((size_t)blockIdx.x * 256 + threadIdx.x) * 4;
  const size_t M4 = 4u << 20;
  const float* src = (i < M4) ? a : b;
  const size_t off = (i < M4) ? i : i - M4;
  const float4 v = *(const float4*)(src + off);
  bf16x4 o = {(bf16)v.x, (bf16)v.y, (bf16)v.z, (bf16)v.w};
  *(bf16x4*)(dst + i) = o;
}

// ---------------------------------------------------------------------------
// GEMM: C[M,N] = A[M,K] * B[N,K]^T  (+ optional second A accumulated, epilogue)
// EPI: 0 = f32 store, 2 = f32(acc + R[f32]), 3 = bf16 gelu(acc),
//      4 = split bf16 hi/lo of (acc*scale)  (Cv=hi, C2=lo),
//      5 = bf16 store transposed to V^T global layout (b,h,d,t)
// 128x128 tile, BK=32, 256 threads = 4 waves (2x2 of 64x64), mfma 16x16x32 bf16
// ---------------------------------------------------------------------------
template <int EPI, bool SPLIT>
static __device__ __forceinline__ void gemm_body(
    const bf16* __restrict__ A, const bf16* __restrict__ A2,
    const bf16* __restrict__ B, void* __restrict__ Cv, void* __restrict__ C2,
    const float* __restrict__ R, float scale, int col0, int row0, int M, int N,
    int K) {
  __shared__ bf16 sA[128 * 32];
  __shared__ bf16 sB[128 * 32];
  const int tid = threadIdx.x;
  const int lane = tid & 63;
  const int wid = tid >> 6;
  const int wm = wid >> 1, wn = wid & 1;

  f32x4 acc[4][4];
  const f32x4 fzero = {0.f, 0.f, 0.f, 0.f};
#pragma unroll
  for (int i = 0; i < 4; ++i)
#pragma unroll
    for (int j = 0; j < 4; ++j) acc[i][j] = fzero;

  const int nk = K >> 5;
  const int total = SPLIT ? (nk << 1) : nk;
  const int r0 = tid >> 2, c0 = (tid & 3) << 3;
  const int r1 = (256 + tid) >> 2, c1 = ((256 + tid) & 3) << 3;
  bf16* lA0 = sA + (wid << 6) * 8;  // wave-uniform LDS bases
  bf16* lA1 = sA + (256 + (wid << 6)) * 8;
  bf16* lB0 = sB + (wid << 6) * 8;
  bf16* lB1 = sB + (256 + (wid << 6)) * 8;

  for (int kt = 0; kt < total; ++kt) {
    const int kk = (kt < nk) ? kt : kt - nk;
    const bf16* Ap = (SPLIT && kt >= nk) ? A2 : A;
    const int k0 = kk << 5;
    async16(Ap + (size_t)(row0 + r0) * K + k0 + c0, lA0);
    async16(Ap + (size_t)(row0 + r1) * K + k0 + c1, lA1);
    async16(B + (size_t)(col0 + r0) * K + k0 + c0, lB0);
    async16(B + (size_t)(col0 + r1) * K + k0 + c1, lB1);
    __syncthreads();
    const int fr = lane & 15, fq = (lane >> 4) << 3;
    bf16x8 af[4], bfr[4];
#pragma unroll
    for (int i = 0; i < 4; ++i)
      af[i] = *(const bf16x8*)&sA[(wm * 64 + i * 16 + fr) * 32 + fq];
#pragma unroll
    for (int j = 0; j < 4; ++j)
      bfr[j] = *(const bf16x8*)&sB[(wn * 64 + j * 16 + fr) * 32 + fq];
#pragma unroll
    for (int i = 0; i < 4; ++i)
#pragma unroll
      for (int j = 0; j < 4; ++j)
        acc[i][j] = __builtin_amdgcn_mfma_f32_16x16x32_bf16(af[i], bfr[j],
                                                            acc[i][j], 0, 0, 0);
    __syncthreads();
  }

  // C/D layout (m89-verified): col = lane&15, row = (lane>>4)*4 + reg
  const int fr = lane & 15, fq4 = (lane >> 4) << 2;
#pragma unroll
  for (int i = 0; i < 4; ++i) {
#pragma unroll
    for (int j = 0; j < 4; ++j) {
      const int rbase = row0 + wm * 64 + i * 16 + fq4;
      const int col = col0 + wn * 64 + j * 16 + fr;
      if constexpr (EPI == 5) {
        // V^T global: (b, h, d, t); rows rbase..rbase+3 are consecutive t
        const int b = rbase >> 11, t = rbase & 2047;
        const int hh = col >> 6, d = col & 63;
        bf16x4 o4 = {(bf16)acc[i][j][0], (bf16)acc[i][j][1],
                     (bf16)acc[i][j][2], (bf16)acc[i][j][3]};
        *(bf16x4*)&((bf16*)Cv)[(((size_t)(b * 16 + hh)) * 64 + d) * 2048 + t] =
            o4;
      } else {
#pragma unroll
        for (int r = 0; r < 4; ++r) {
          const size_t idx = (size_t)(rbase + r) * N + col;
          const float val = acc[i][j][r];
          if constexpr (EPI == 0) {
            ((float*)Cv)[idx] = val;
          } else if constexpr (EPI == 2) {
            ((float*)Cv)[idx] = val + R[idx];
          } else if constexpr (EPI == 3) {
            ((bf16*)Cv)[idx] =
                (bf16)(0.5f * val * (1.0f + erff(val * 0.7071067811865476f)));
          } else {  // EPI == 4: split hi/lo bf16 of val*scale
            const float vs = val * scale;
            const bf16 hi = (bf16)vs;
            ((bf16*)Cv)[idx] = hi;
            ((bf16*)C2)[idx] = (bf16)(vs - (float)hi);
          }
        }
      }
    }
  }
}

template <int EPI, bool SPLIT>
__global__ __launch_bounds__(256) void gemm_bt(
    const bf16* __restrict__ A, const bf16* __restrict__ A2,
    const bf16* __restrict__ B, void* __restrict__ Cv,
    const float* __restrict__ R, int M, int N, int K) {
  gemm_body<EPI, SPLIT>(A, A2, B, Cv, nullptr, R, 1.0f, blockIdx.x * 128,
                        blockIdx.y * 128, M, N, K);
}

// ---------------------------------------------------------------------------
// 128x64-tile GEMM variant for N=1024 outputs (2 blocks/CU instead of 1):
// 4 waves as 2x2, wave tile 64x32, sB = 64x32, 3 async16 + 8 MFMA per iter.
// EPI semantics as above (only 2 used).
// ---------------------------------------------------------------------------
template <int EPI>
__global__ __launch_bounds__(256) void gemm_bt64(
    const bf16* __restrict__ A, const bf16* __restrict__ B,
    void* __restrict__ Cv, const float* __restrict__ R, int M, int N, int K) {
  __shared__ bf16 sA[128 * 32];
  __shared__ bf16 sB[64 * 32];
  const int col0 = blockIdx.x * 64, row0 = blockIdx.y * 128;
  const int tid = threadIdx.x;
  const int lane = tid & 63;
  const int wid = tid >> 6;
  const int wm = wid >> 1, wn = wid & 1;

  f32x4 acc[4][2];
  const f32x4 fzero = {0.f, 0.f, 0.f, 0.f};
#pragma unroll
  for (int i = 0; i < 4; ++i)
#pragma unroll
    for (int j = 0; j < 2; ++j) acc[i][j] = fzero;

  const int nk = K >> 5;
  const int r0 = tid >> 2, c0 = (tid & 3) << 3;
  const int r1 = (256 + tid) >> 2, c1 = ((256 + tid) & 3) << 3;
  bf16* lA0 = sA + (wid << 6) * 8;
  bf16* lA1 = sA + (256 + (wid << 6)) * 8;
  bf16* lB0 = sB + (wid << 6) * 8;

  for (int kt = 0; kt < nk; ++kt) {
    const int k0 = kt << 5;
    async16(A + (size_t)(row0 + r0) * K + k0 + c0, lA0);
    async16(A + (size_t)(row0 + r1) * K + k0 + c1, lA1);
    async16(B + (size_t)(col0 + r0) * K + k0 + c0, lB0);
    __syncthreads();
    const int fr = lane & 15, fq = (lane >> 4) << 3;
    bf16x8 af[4], bfr[2];
#pragma unroll
    for (int i = 0; i < 4; ++i)
      af[i] = *(const bf16x8*)&sA[(wm * 64 + i * 16 + fr) * 32 + fq];
#pragma unroll
    for (int j = 0; j < 2; ++j)
      bfr[j] = *(const bf16x8*)&sB[(wn * 32 + j * 16 + fr) * 32 + fq];
#pragma unroll
    for (int i = 0; i < 4; ++i)
#pragma unroll
      for (int j = 0; j < 2; ++j)
        acc[i][j] = __builtin_amdgcn_mfma_f32_16x16x32_bf16(af[i], bfr[j],
                                                            acc[i][j], 0, 0, 0);
    __syncthreads();
  }

  const int fr = lane & 15, fq4 = (lane >> 4) << 2;
#pragma unroll
  for (int i = 0; i < 4; ++i) {
#pragma unroll
    for (int j = 0; j < 2; ++j) {
      const int rbase = row0 + wm * 64 + i * 16 + fq4;
      const int col = col0 + wn * 32 + j * 16 + fr;
#pragma unroll
      for (int r = 0; r < 4; ++r) {
        const size_t idx = (size_t)(rbase + r) * N + col;
        const float val = acc[i][j][r];
        if constexpr (EPI == 2) {
          ((float*)Cv)[idx] = val + R[idx];
        } else {
          ((float*)Cv)[idx] = val;
        }
      }
    }
  }
}

// Q,K,V fused: grid (24, 32). bx>>3: 0=q (split, scaled 1/8), 1=k (split),
// 2=v (single-pass bf16 h, transposed store).
__global__ __launch_bounds__(256) void gemm_qkv(
    const bf16* __restrict__ A, const bf16* __restrict__ A2,
    const bf16* __restrict__ Bq, const bf16* __restrict__ Bk,
    const bf16* __restrict__ Bv, bf16* qh, bf16* ql, bf16* kh, bf16* kl,
    bf16* vt) {
  const int which = blockIdx.x >> 3;
  const int col0 = (blockIdx.x & 7) * 128, row0 = blockIdx.y * 128;
  if (which == 2) {
    gemm_body<5, false>(A, nullptr, Bv, (void*)vt, nullptr, nullptr, 1.0f,
                        col0, row0, 4096, 1024, 1024);
  } else {
    gemm_body<4, true>(A, A2, which ? Bk : Bq, which ? (void*)kh : (void*)qh,
                       which ? (void*)kl : (void*)ql, nullptr,
                       which ? 1.0f : 0.125f, col0, row0, 4096, 1024, 1024);
  }
}

// ---------------------------------------------------------------------------
// LayerNorm over D=1024 (f32 input), one block per row.
// ---------------------------------------------------------------------------
template <bool SPLIT>
__global__ __launch_bounds__(256) void ln_kernel(
    const float* __restrict__ x, const float* __restrict__ g,
    const float* __restrict__ b, bf16* __restrict__ hi, bf16* __restrict__ lo) {
  const int row = blockIdx.x;
  const int tid = threadIdx.x;
  const float* xr = x + (size_t)row * 1024;
  float v[4];
  float s1 = 0.f, s2 = 0.f;
#pragma unroll
  for (int j = 0; j < 4; ++j) {
    v[j] = xr[j * 256 + tid];
    s1 += v[j];
    s2 += v[j] * v[j];
  }
#pragma unroll
  for (int off = 1; off < 64; off <<= 1) {
    s1 += __shfl_xor(s1, off);
    s2 += __shfl_xor(s2, off);
  }
  __shared__ float ws1[4], ws2[4];
  const int wid = tid >> 6;
  if ((tid & 63) == 0) {
    ws1[wid] = s1;
    ws2[wid] = s2;
  }
  __syncthreads();
  s1 = ws1[0] + ws1[1] + ws1[2] + ws1[3];
  s2 = ws2[0] + ws2[1] + ws2[2] + ws2[3];
  const float mu = s1 * (1.f / 1024.f);
  const float var = s2 * (1.f / 1024.f) - mu * mu;
  const float rstd = 1.0f / sqrtf(var + 1e-5f);
#pragma unroll
  for (int j = 0; j < 4; ++j) {
    const int cc = j * 256 + tid;
    const float y = (v[j] - mu) * rstd * g[cc] + b[cc];
    const bf16 yh = (bf16)y;
    hi[(size_t)row * 1024 + cc] = yh;
    if constexpr (SPLIT) lo[(size_t)row * 1024 + cc] = (bf16)(y - (float)yh);
  }
}

// ---------------------------------------------------------------------------
// MFMA causal flash attention, latency-optimized.
//  - Q fragments loaded straight from global (no Q LDS region)
//  - next K/V tile prefetched into registers during current tile's compute
//  - 2 barriers/iter; P tile wave-private (own region, stride 76, no barrier)
//  - LDS 37376 B -> 4 blocks/CU
//  - plain __launch_bounds__(256): the (256,4) variant made the allocator
//    squeeze to 64 VGPRs and SPILL (WRITE_SIZE 8->29 MB) — do not re-add.
// Split-bf16 Q,K: S = qh*kh + qh*kl + ql*kh (lo*lo ~3e-3, below budget).
// Long blocks (qt=31) launched first to beat causal imbalance.
// ---------------------------------------------------------------------------
__global__ __launch_bounds__(256) void attn_kernel(
    const bf16* __restrict__ qh_g, const bf16* __restrict__ ql_g,
    const bf16* __restrict__ kh_g, const bf16* __restrict__ kl_g,
    const bf16* __restrict__ vt_g, bf16* __restrict__ out) {
  __shared__ bf16 lds[18688];  // 37376 B
  bf16* Kh = lds;              // 64 x 72
  bf16* Kl = lds + 4608;       // 64 x 72
  bf16* Vt = lds + 9216;       // 64 x 72, rows = dim d, cols = key
  bf16* Ps = lds + 13824;      // 64 x 76 (wave-private 16-row blocks)

  const int bid = blockIdx.x;
  const int qt = 31 - (bid >> 5);  // long blocks first
  const int h = bid & 15;
  const int b = (bid >> 4) & 1;
  const int t0 = qt << 6;
  const int tid = threadIdx.x;
  const int w = tid >> 6;
  const int lane = tid & 63;
  const int c = lane & 15;
  const int quad = lane >> 4;

  // staging map: chunk idx -> (row idx>>3, col8 (idx&7)*8)
  const int r0 = tid >> 3, c0 = (tid & 7) << 3;
  const int r1 = (tid + 256) >> 3, c1 = ((tid + 256) & 7) << 3;

  // Q fragments straight from global (once per block)
  const size_t qrow =
      ((size_t)(b * 2048 + t0 + w * 16 + c)) * 1024 + h * 64 + quad * 8;
  bf16x8 aqh[2], aql[2];
  aqh[0] = *(const bf16x8*)&qh_g[qrow];
  aqh[1] = *(const bf16x8*)&qh_g[qrow + 32];
  aql[0] = *(const bf16x8*)&ql_g[qrow];
  aql[1] = *(const bf16x8*)&ql_g[qrow + 32];

  f32x4 o[4];
  const f32x4 fzero = {0.f, 0.f, 0.f, 0.f};
#pragma unroll
  for (int j = 0; j < 4; ++j) o[j] = fzero;
  float m_i[4] = {-3e38f, -3e38f, -3e38f, -3e38f};
  float l_i[4] = {0.f, 0.f, 0.f, 0.f};

  const size_t vtb = ((size_t)(b * 16 + h)) * 64 * 2048;  // + d*2048 + t
  const size_t kband = ((size_t)(b * 2048)) * 1024 + h * 64;

  bf16x8 gk[6];  // register prefetch of next K/V tile
  {
    gk[0] = *(const bf16x8*)&kh_g[kband + (size_t)r0 * 1024 + c0];
    gk[1] = *(const bf16x8*)&kh_g[kband + (size_t)r1 * 1024 + c1];
    gk[2] = *(const bf16x8*)&kl_g[kband + (size_t)r0 * 1024 + c0];
    gk[3] = *(const bf16x8*)&kl_g[kband + (size_t)r1 * 1024 + c1];
    gk[4] = *(const bf16x8*)&vt_g[vtb + (size_t)r0 * 2048 + c0];
    gk[5] = *(const bf16x8*)&vt_g[vtb + (size_t)r1 * 2048 + c1];
  }

  for (int kt = 0; kt <= qt; ++kt) {
    __syncthreads();  // (A) prev tile's fragment reads done before restage
    *(bf16x8*)&Kh[r0 * 72 + c0] = gk[0];
    *(bf16x8*)&Kh[r1 * 72 + c1] = gk[1];
    *(bf16x8*)&Kl[r0 * 72 + c0] = gk[2];
    *(bf16x8*)&Kl[r1 * 72 + c1] = gk[3];
    *(bf16x8*)&Vt[r0 * 72 + c0] = gk[4];
    *(bf16x8*)&Vt[r1 * 72 + c1] = gk[5];
    __syncthreads();  // (B) staging visible

    if (kt < qt) {  // prefetch next tile; latency hidden behind compute
      const int kb1 = (kt + 1) << 6;
      const size_t kbase = kband + (size_t)kb1 * 1024;
      gk[0] = *(const bf16x8*)&kh_g[kbase + (size_t)r0 * 1024 + c0];
      gk[1] = *(const bf16x8*)&kh_g[kbase + (size_t)r1 * 1024 + c1];
      gk[2] = *(const bf16x8*)&kl_g[kbase + (size_t)r0 * 1024 + c0];
      gk[3] = *(const bf16x8*)&kl_g[kbase + (size_t)r1 * 1024 + c1];
      gk[4] = *(const bf16x8*)&vt_g[vtb + (size_t)r0 * 2048 + kb1 + c0];
      gk[5] = *(const bf16x8*)&vt_g[vtb + (size_t)r1 * 2048 + kb1 + c1];
    }

    bf16x8 bkh[4][2], bkl[4][2];
#pragma unroll
    for (int j = 0; j < 4; ++j)
#pragma unroll
      for (int s = 0; s < 2; ++s) {
        bkh[j][s] = *(const bf16x8*)&Kh[(j * 16 + c) * 72 + s * 32 + quad * 8];
        bkl[j][s] = *(const bf16x8*)&Kl[(j * 16 + c) * 72 + s * 32 + quad * 8];
      }

    f32x4 s4[4];
#pragma unroll
    for (int j = 0; j < 4; ++j) s4[j] = fzero;
#pragma unroll
    for (int j = 0; j < 4; ++j)
#pragma unroll
      for (int s = 0; s < 2; ++s) {
        s4[j] = __builtin_amdgcn_mfma_f32_16x16x32_bf16(aqh[s], bkh[j][s], s4[j], 0, 0, 0);
        s4[j] = __builtin_amdgcn_mfma_f32_16x16x32_bf16(aqh[s], bkl[j][s], s4[j], 0, 0, 0);
        s4[j] = __builtin_amdgcn_mfma_f32_16x16x32_bf16(aql[s], bkh[j][s], s4[j], 0, 0, 0);
      }

    if (kt == qt) {  // diagonal tile: strict-upper mask (t0 == kb)
#pragma unroll
      for (int j = 0; j < 4; ++j)
#pragma unroll
        for (int r = 0; r < 4; ++r)
          if (j * 16 + c > w * 16 + quad * 4 + r) s4[j][r] = -3e38f;
    }

    float al[4], p[4][4];
#pragma unroll
    for (int r = 0; r < 4; ++r) {
      float mt = fmaxf(fmaxf(s4[0][r], s4[1][r]), fmaxf(s4[2][r], s4[3][r]));
#pragma unroll
      for (int off = 1; off < 16; off <<= 1) mt = fmaxf(mt, __shfl_xor(mt, off));
      const float mn = fmaxf(m_i[r], mt);
      al[r] = __expf(m_i[r] - mn);
      float ps = 0.f;
#pragma unroll
      for (int j = 0; j < 4; ++j) {
        p[r][j] = __expf(s4[j][r] - mn);
        ps += p[r][j];
      }
#pragma unroll
      for (int off = 1; off < 16; off <<= 1) ps += __shfl_xor(ps, off);
      l_i[r] = l_i[r] * al[r] + ps;
      m_i[r] = mn;
#pragma unroll
      for (int j = 0; j < 4; ++j) o[j][r] *= al[r];
    }

    // P -> wave-private region, stride 76 (conflict-free; intra-wave RAW only)
    bf16* Pw = Ps + w * 16 * 76;
#pragma unroll
    for (int r = 0; r < 4; ++r)
#pragma unroll
      for (int j = 0; j < 4; ++j)
        Pw[(quad * 4 + r) * 76 + j * 16 + c] = (bf16)p[r][j];

    bf16x8 ap[2], bv[4][2];
#pragma unroll
    for (int s = 0; s < 2; ++s)
      ap[s] = *(const bf16x8*)&Pw[c * 76 + s * 32 + quad * 8];
#pragma unroll
    for (int j = 0; j < 4; ++j)
#pragma unroll
      for (int s = 0; s < 2; ++s)
        bv[j][s] = *(const bf16x8*)&Vt[(j * 16 + c) * 72 + s * 32 + quad * 8];
#pragma unroll
    for (int j = 0; j < 4; ++j)
#pragma unroll
      for (int s = 0; s < 2; ++s)
        o[j] = __builtin_amdgcn_mfma_f32_16x16x32_bf16(ap[s], bv[j][s], o[j], 0, 0, 0);
  }

#pragma unroll
  for (int r = 0; r < 4; ++r) {
    const float inv = 1.0f / l_i[r];
#pragma unroll
    for (int j = 0; j < 4; ++j) {
      const size_t oi =
          ((size_t)(b * 2048 + t0 + w * 16 + quad * 4 + r)) * 1024 + h * 64 +
          j * 16 + c;
      out[oi] = (bf16)(o[j][r] * inv);
    }
  }
}

// ---------------------------------------------------------------------------
// Workspace plan (80 MiB peak; >104 MiB previously corrupted harness memory):
//   [ 0, 8)   Wq|Wk|Wv|Wo bf16
//   [ 8,24)   h_hi|h_lo  -> (after gemm_qkv) Wf1_b|Wf2_b   (cvt2 overwrite)
//   [24,40)   qh|ql      -> (after attn)   x1 (f32)
//   [40,72)   kh|kl|vt|attnout -> (after k4) ff (bf16 4096x4096)
//   [72,80)   h2
// ---------------------------------------------------------------------------
extern "C" void kernel_launch(void* const* d_in, const int* in_sizes, int n_in,
                              void* d_out, int out_size, void* d_ws,
                              size_t ws_size, hipStream_t stream) {
  const float* x = (const float*)d_in[0];
  const float* g1 = (const float*)d_in[2];
  const float* b1 = (const float*)d_in[3];
  const float* g2 = (const float*)d_in[4];
  const float* b2 = (const float*)d_in[5];
  const float* Wq = (const float*)d_in[6];
  const float* Wk = (const float*)d_in[7];
  const float* Wv = (const float*)d_in[8];
  const float* Wo = (const float*)d_in[9];
  const float* Wf1 = (const float*)d_in[10];
  const float* Wf2 = (const float*)d_in[11];
  char* ws = (char*)d_ws;
  const size_t MB = 1024 * 1024;
  const size_t M1 = 1u << 20;
  bf16* Wq_b = (bf16*)ws;
  bf16* Wk_b = Wq_b + 1 * M1;
  bf16* Wv_b = Wq_b + 2 * M1;
  bf16* Wo_b = Wq_b + 3 * M1;
  bf16* h_hi = (bf16*)(ws + 8 * MB);
  bf16* h_lo = (bf16*)(ws + 16 * MB);
  bf16* Wf1_b = h_hi;  // alias: h dead after gemm_qkv; cvt2 fills before k6
  bf16* Wf2_b = h_lo;
  bf16* qh = (bf16*)(ws + 24 * MB);
  bf16* ql = (bf16*)(ws + 32 * MB);
  bf16* kh = (bf16*)(ws + 40 * MB);
  bf16* kl = (bf16*)(ws + 48 * MB);
  bf16* vt = (bf16*)(ws + 56 * MB);
  bf16* attnout = (bf16*)(ws + 64 * MB);
  float* x1 = (float*)qh;  // alias: qh/ql dead after attn
  bf16* h2 = (bf16*)(ws + 72 * MB);
  bf16* ff = kh;  // alias: kh/kl/vt/attnout dead after k4
  float* outp = (float*)d_out;

  // 0) attention-path weights f32 -> bf16 (exact for ternary)
  cvt4<<<4096, 256, 0, stream>>>(Wq, Wk, Wv, Wo, Wq_b);
  // 1) LN1 -> split bf16 hi/lo
  ln_kernel<true><<<4096, 256, 0, stream>>>(x, g1, b1, h_hi, h_lo);
  // 2) Q,K (split bf16, q pre-scaled 1/8) + V^T (single-pass bf16) fused
  gemm_qkv<<<dim3(24, 32), 256, 0, stream>>>(h_hi, h_lo, Wq_b, Wk_b, Wv_b, qh,
                                             ql, kh, kl, vt);
  // 2.5) h is dead now: convert FF weights into its slot
  cvt2<<<8192, 256, 0, stream>>>(Wf1, Wf2, Wf1_b);
  // 3) MFMA causal flash attention -> bf16 (B,T,1024)
  attn_kernel<<<1024, 256, 0, stream>>>(qh, ql, kh, kl, vt, attnout);
  // 4) x1 = x + attnout @ Wo^T   (f32; overwrites dead qh/ql) — 64N tiles
  gemm_bt64<2><<<dim3(16, 32), 256, 0, stream>>>(attnout, Wo_b, (void*)x1, x,
                                                 4096, 1024, 1024);
  // 5) LN2 -> h2 (bf16)
  ln_kernel<false><<<4096, 256, 0, stream>>>(x1, g2, b2, h2, nullptr);
  // 6) ff = gelu(h2 @ Wff1^T)  (bf16; overwrites dead kh/kl/vt/attnout)
  gemm_bt<3, false><<<dim3(32, 32), 256, 0, stream>>>(
      h2, nullptr, Wf1_b, (void*)ff, nullptr, 4096, 4096, 1024);
  // 7) out = x1 + ff @ Wff2^T  (f32) — 64N tiles
  gemm_bt64<2><<<dim3(16, 32), 256, 0, stream>>>(ff, Wf2_b, (void*)outp, x1,
                                                 4096, 1024, 4096);
}

// Round 8
// 465.603 us; speedup vs baseline: 2.2864x; 1.0108x over previous
//
#include <hip/hip_runtime.h>

typedef __bf16 bf16;
typedef bf16 bf16x8 __attribute__((ext_vector_type(8)));
typedef bf16 bf16x4 __attribute__((ext_vector_type(4)));
typedef float f32x4 __attribute__((ext_vector_type(4)));

// ---------------------------------------------------------------------------
// async global->LDS 16B copy (wave-uniform LDS base + lane*16 placement)
// ---------------------------------------------------------------------------
static __device__ __forceinline__ void async16(const void* g, void* l) {
  __builtin_amdgcn_global_load_lds((__attribute__((address_space(1))) void*)g,
                                   (__attribute__((address_space(3))) void*)l,
                                   16, 0, 0);
}

// DPP row_ror:N within 16-lane rows (VALU-only cross-lane; no LDS pipe).
template <int N>
static __device__ __forceinline__ float ror16(float x) {
  const int y =
      __builtin_amdgcn_update_dpp(0, __float_as_int(x), 0x120 | N, 0xf, 0xf, true);
  return __int_as_float(y);
}
// all-reduce across the 16-lane row: every lane ends with the row result
static __device__ __forceinline__ float rowmax16(float x) {
  x = fmaxf(x, ror16<8>(x));
  x = fmaxf(x, ror16<4>(x));
  x = fmaxf(x, ror16<2>(x));
  x = fmaxf(x, ror16<1>(x));
  return x;
}
static __device__ __forceinline__ float rowsum16(float x) {
  x += ror16<8>(x);
  x += ror16<4>(x);
  x += ror16<2>(x);
  x += ror16<1>(x);
  return x;
}

// ---------------------------------------------------------------------------
// Weight f32 -> bf16 conversion (ternary {-1,0,1}: exact in bf16).
// ---------------------------------------------------------------------------
__global__ __launch_bounds__(256) void cvt4(const float* __restrict__ a,
                                            const float* __restrict__ b,
                                            const float* __restrict__ c,
                                            const float* __restrict__ d,
                                            bf16* __restrict__ dst) {
  const size_t i = ((size_t)blockIdx.x * 256 + threadIdx.x) * 4;
  const size_t M1 = 1u << 20;
  const float* src = (i < M1) ? a : (i < 2 * M1) ? b : (i < 3 * M1) ? c : d;
  const size_t off = i & (M1 - 1);
  const float4 v = *(const float4*)(src + off);
  bf16x4 o = {(bf16)v.x, (bf16)v.y, (bf16)v.z, (bf16)v.w};
  *(bf16x4*)(dst + i) = o;
}

__global__ __launch_bounds__(256) void cvt2(const float* __restrict__ a,
                                            const float* __restrict__ b,
                                            bf16* __restrict__ dst) {
  const size_t i = ((size_t)blockIdx.x * 256 + threadIdx.x) * 4;
  const size_t M4 = 4u << 20;
  const float* src = (i < M4) ? a : b;
  const size_t off = (i < M4) ? i : i - M4;
  const float4 v = *(const float4*)(src + off);
  bf16x4 o = {(bf16)v.x, (bf16)v.y, (bf16)v.z, (bf16)v.w};
  *(bf16x4*)(dst + i) = o;
}

// ---------------------------------------------------------------------------
// GEMM: C[M,N] = A[M,K] * B[N,K]^T  (+ optional second A accumulated, epilogue)
// EPI: 0 = f32 store, 2 = f32(acc + R[f32]), 3 = bf16 gelu(acc),
//      4 = split bf16 hi/lo of (acc*scale)  (Cv=hi, C2=lo),
//      5 = bf16 store transposed to V^T global layout (b,h,d,t)
// 128x128 tile, BK=32, 256 threads = 4 waves (2x2 of 64x64), mfma 16x16x32 bf16
// ---------------------------------------------------------------------------
template <int EPI, bool SPLIT>
static __device__ __forceinline__ void gemm_body(
    const bf16* __restrict__ A, const bf16* __restrict__ A2,
    const bf16* __restrict__ B, void* __restrict__ Cv, void* __restrict__ C2,
    const float* __restrict__ R, float scale, int col0, int row0, int M, int N,
    int K) {
  __shared__ bf16 sA[128 * 32];
  __shared__ bf16 sB[128 * 32];
  const int tid = threadIdx.x;
  const int lane = tid & 63;
  const int wid = tid >> 6;
  const int wm = wid >> 1, wn = wid & 1;

  f32x4 acc[4][4];
  const f32x4 fzero = {0.f, 0.f, 0.f, 0.f};
#pragma unroll
  for (int i = 0; i < 4; ++i)
#pragma unroll
    for (int j = 0; j < 4; ++j) acc[i][j] = fzero;

  const int nk = K >> 5;
  const int total = SPLIT ? (nk << 1) : nk;
  const int r0 = tid >> 2, c0 = (tid & 3) << 3;
  const int r1 = (256 + tid) >> 2, c1 = ((256 + tid) & 3) << 3;
  bf16* lA0 = sA + (wid << 6) * 8;  // wave-uniform LDS bases
  bf16* lA1 = sA + (256 + (wid << 6)) * 8;
  bf16* lB0 = sB + (wid << 6) * 8;
  bf16* lB1 = sB + (256 + (wid << 6)) * 8;

  for (int kt = 0; kt < total; ++kt) {
    const int kk = (kt < nk) ? kt : kt - nk;
    const bf16* Ap = (SPLIT && kt >= nk) ? A2 : A;
    const int k0 = kk << 5;
    async16(Ap + (size_t)(row0 + r0) * K + k0 + c0, lA0);
    async16(Ap + (size_t)(row0 + r1) * K + k0 + c1, lA1);
    async16(B + (size_t)(col0 + r0) * K + k0 + c0, lB0);
    async16(B + (size_t)(col0 + r1) * K + k0 + c1, lB1);
    __syncthreads();
    const int fr = lane & 15, fq = (lane >> 4) << 3;
    bf16x8 af[4], bfr[4];
#pragma unroll
    for (int i = 0; i < 4; ++i)
      af[i] = *(const bf16x8*)&sA[(wm * 64 + i * 16 + fr) * 32 + fq];
#pragma unroll
    for (int j = 0; j < 4; ++j)
      bfr[j] = *(const bf16x8*)&sB[(wn * 64 + j * 16 + fr) * 32 + fq];
#pragma unroll
    for (int i = 0; i < 4; ++i)
#pragma unroll
      for (int j = 0; j < 4; ++j)
        acc[i][j] = __builtin_amdgcn_mfma_f32_16x16x32_bf16(af[i], bfr[j],
                                                            acc[i][j], 0, 0, 0);
    __syncthreads();
  }

  // C/D layout (m89-verified): col = lane&15, row = (lane>>4)*4 + reg
  const int fr = lane & 15, fq4 = (lane >> 4) << 2;
#pragma unroll
  for (int i = 0; i < 4; ++i) {
#pragma unroll
    for (int j = 0; j < 4; ++j) {
      const int rbase = row0 + wm * 64 + i * 16 + fq4;
      const int col = col0 + wn * 64 + j * 16 + fr;
      if constexpr (EPI == 5) {
        // V^T global: (b, h, d, t); rows rbase..rbase+3 are consecutive t
        const int b = rbase >> 11, t = rbase & 2047;
        const int hh = col >> 6, d = col & 63;
        bf16x4 o4 = {(bf16)acc[i][j][0], (bf16)acc[i][j][1],
                     (bf16)acc[i][j][2], (bf16)acc[i][j][3]};
        *(bf16x4*)&((bf16*)Cv)[(((size_t)(b * 16 + hh)) * 64 + d) * 2048 + t] =
            o4;
      } else {
#pragma unroll
        for (int r = 0; r < 4; ++r) {
          const size_t idx = (size_t)(rbase + r) * N + col;
          const float val = acc[i][j][r];
          if constexpr (EPI == 0) {
            ((float*)Cv)[idx] = val;
          } else if constexpr (EPI == 2) {
            ((float*)Cv)[idx] = val + R[idx];
          } else if constexpr (EPI == 3) {
            ((bf16*)Cv)[idx] =
                (bf16)(0.5f * val * (1.0f + erff(val * 0.7071067811865476f)));
          } else {  // EPI == 4: split hi/lo bf16 of val*scale
            const float vs = val * scale;
            const bf16 hi = (bf16)vs;
            ((bf16*)Cv)[idx] = hi;
            ((bf16*)C2)[idx] = (bf16)(vs - (float)hi);
          }
        }
      }
    }
  }
}

template <int EPI, bool SPLIT>
__global__ __launch_bounds__(256) void gemm_bt(
    const bf16* __restrict__ A, const bf16* __restrict__ A2,
    const bf16* __restrict__ B, void* __restrict__ Cv,
    const float* __restrict__ R, int M, int N, int K) {
  gemm_body<EPI, SPLIT>(A, A2, B, Cv, nullptr, R, 1.0f, blockIdx.x * 128,
                        blockIdx.y * 128, M, N, K);
}

// ---------------------------------------------------------------------------
// Merged split-K GEMM for q/k: stages A_hi, A_lo AND B each k-step (B loaded
// ONCE, 32 iters instead of 64, half the barriers). Epilogue = EPI4.
// ---------------------------------------------------------------------------
static __device__ __forceinline__ void gemm_split_merged(
    const bf16* __restrict__ A, const bf16* __restrict__ A2,
    const bf16* __restrict__ B, bf16* __restrict__ Chi, bf16* __restrict__ Clo,
    float scale, int col0, int row0) {
  constexpr int K = 1024, N = 1024;
  __shared__ bf16 sAh[128 * 32];
  __shared__ bf16 sAl[128 * 32];
  __shared__ bf16 sB[128 * 32];
  const int tid = threadIdx.x;
  const int lane = tid & 63;
  const int wid = tid >> 6;
  const int wm = wid >> 1, wn = wid & 1;

  f32x4 acc[4][4];
  const f32x4 fzero = {0.f, 0.f, 0.f, 0.f};
#pragma unroll
  for (int i = 0; i < 4; ++i)
#pragma unroll
    for (int j = 0; j < 4; ++j) acc[i][j] = fzero;

  const int r0 = tid >> 2, c0 = (tid & 3) << 3;
  const int r1 = (256 + tid) >> 2, c1 = ((256 + tid) & 3) << 3;
  bf16* lAh0 = sAh + (wid << 6) * 8;
  bf16* lAh1 = sAh + (256 + (wid << 6)) * 8;
  bf16* lAl0 = sAl + (wid << 6) * 8;
  bf16* lAl1 = sAl + (256 + (wid << 6)) * 8;
  bf16* lB0 = sB + (wid << 6) * 8;
  bf16* lB1 = sB + (256 + (wid << 6)) * 8;

  for (int kt = 0; kt < 32; ++kt) {
    const int k0 = kt << 5;
    async16(A + (size_t)(row0 + r0) * K + k0 + c0, lAh0);
    async16(A + (size_t)(row0 + r1) * K + k0 + c1, lAh1);
    async16(A2 + (size_t)(row0 + r0) * K + k0 + c0, lAl0);
    async16(A2 + (size_t)(row0 + r1) * K + k0 + c1, lAl1);
    async16(B + (size_t)(col0 + r0) * K + k0 + c0, lB0);
    async16(B + (size_t)(col0 + r1) * K + k0 + c1, lB1);
    __syncthreads();
    const int fr = lane & 15, fq = (lane >> 4) << 3;
    bf16x8 ah[4], al[4], bfr[4];
#pragma unroll
    for (int i = 0; i < 4; ++i) {
      ah[i] = *(const bf16x8*)&sAh[(wm * 64 + i * 16 + fr) * 32 + fq];
      al[i] = *(const bf16x8*)&sAl[(wm * 64 + i * 16 + fr) * 32 + fq];
    }
#pragma unroll
    for (int j = 0; j < 4; ++j)
      bfr[j] = *(const bf16x8*)&sB[(wn * 64 + j * 16 + fr) * 32 + fq];
#pragma unroll
    for (int i = 0; i < 4; ++i)
#pragma unroll
      for (int j = 0; j < 4; ++j) {
        acc[i][j] = __builtin_amdgcn_mfma_f32_16x16x32_bf16(ah[i], bfr[j],
                                                            acc[i][j], 0, 0, 0);
        acc[i][j] = __builtin_amdgcn_mfma_f32_16x16x32_bf16(al[i], bfr[j],
                                                            acc[i][j], 0, 0, 0);
      }
    __syncthreads();
  }

  const int fr = lane & 15, fq4 = (lane >> 4) << 2;
#pragma unroll
  for (int i = 0; i < 4; ++i)
#pragma unroll
    for (int j = 0; j < 4; ++j) {
      const int rbase = row0 + wm * 64 + i * 16 + fq4;
      const int col = col0 + wn * 64 + j * 16 + fr;
#pragma unroll
      for (int r = 0; r < 4; ++r) {
        const size_t idx = (size_t)(rbase + r) * N + col;
        const float vs = acc[i][j][r] * scale;
        const bf16 hi = (bf16)vs;
        Chi[idx] = hi;
        Clo[idx] = (bf16)(vs - (float)hi);
      }
    }
}

// Q,K,V fused: grid (24, 32). bx>>3: 0=q (merged split, scaled 1/8),
// 1=k (merged split), 2=v (single-pass bf16 h, transposed store).
__global__ __launch_bounds__(256) void gemm_qkv(
    const bf16* __restrict__ A, const bf16* __restrict__ A2,
    const bf16* __restrict__ Bq, const bf16* __restrict__ Bk,
    const bf16* __restrict__ Bv, bf16* qh, bf16* ql, bf16* kh, bf16* kl,
    bf16* vt) {
  const int which = blockIdx.x >> 3;
  const int col0 = (blockIdx.x & 7) * 128, row0 = blockIdx.y * 128;
  if (which == 2) {
    gemm_body<5, false>(A, nullptr, Bv, (void*)vt, nullptr, nullptr, 1.0f,
                        col0, row0, 4096, 1024, 1024);
  } else {
    gemm_split_merged(A, A2, which ? Bk : Bq, which ? kh : qh, which ? kl : ql,
                      which ? 1.0f : 0.125f, col0, row0);
  }
}

// ---------------------------------------------------------------------------
// 128x64-tile GEMM variant for N=1024 outputs (2 blocks/CU instead of 1).
// ---------------------------------------------------------------------------
template <int EPI>
__global__ __launch_bounds__(256) void gemm_bt64(
    const bf16* __restrict__ A, const bf16* __restrict__ B,
    void* __restrict__ Cv, const float* __restrict__ R, int M, int N, int K) {
  __shared__ bf16 sA[128 * 32];
  __shared__ bf16 sB[64 * 32];
  const int col0 = blockIdx.x * 64, row0 = blockIdx.y * 128;
  const int tid = threadIdx.x;
  const int lane = tid & 63;
  const int wid = tid >> 6;
  const int wm = wid >> 1, wn = wid & 1;

  f32x4 acc[4][2];
  const f32x4 fzero = {0.f, 0.f, 0.f, 0.f};
#pragma unroll
  for (int i = 0; i < 4; ++i)
#pragma unroll
    for (int j = 0; j < 2; ++j) acc[i][j] = fzero;

  const int nk = K >> 5;
  const int r0 = tid >> 2, c0 = (tid & 3) << 3;
  const int r1 = (256 + tid) >> 2, c1 = ((256 + tid) & 3) << 3;
  bf16* lA0 = sA + (wid << 6) * 8;
  bf16* lA1 = sA + (256 + (wid << 6)) * 8;
  bf16* lB0 = sB + (wid << 6) * 8;

  for (int kt = 0; kt < nk; ++kt) {
    const int k0 = kt << 5;
    async16(A + (size_t)(row0 + r0) * K + k0 + c0, lA0);
    async16(A + (size_t)(row0 + r1) * K + k0 + c1, lA1);
    async16(B + (size_t)(col0 + r0) * K + k0 + c0, lB0);
    __syncthreads();
    const int fr = lane & 15, fq = (lane >> 4) << 3;
    bf16x8 af[4], bfr[2];
#pragma unroll
    for (int i = 0; i < 4; ++i)
      af[i] = *(const bf16x8*)&sA[(wm * 64 + i * 16 + fr) * 32 + fq];
#pragma unroll
    for (int j = 0; j < 2; ++j)
      bfr[j] = *(const bf16x8*)&sB[(wn * 32 + j * 16 + fr) * 32 + fq];
#pragma unroll
    for (int i = 0; i < 4; ++i)
#pragma unroll
      for (int j = 0; j < 2; ++j)
        acc[i][j] = __builtin_amdgcn_mfma_f32_16x16x32_bf16(af[i], bfr[j],
                                                            acc[i][j], 0, 0, 0);
    __syncthreads();
  }

  const int fr = lane & 15, fq4 = (lane >> 4) << 2;
#pragma unroll
  for (int i = 0; i < 4; ++i) {
#pragma unroll
    for (int j = 0; j < 2; ++j) {
      const int rbase = row0 + wm * 64 + i * 16 + fq4;
      const int col = col0 + wn * 32 + j * 16 + fr;
#pragma unroll
      for (int r = 0; r < 4; ++r) {
        const size_t idx = (size_t)(rbase + r) * N + col;
        const float val = acc[i][j][r];
        if constexpr (EPI == 2) {
          ((float*)Cv)[idx] = val + R[idx];
        } else {
          ((float*)Cv)[idx] = val;
        }
      }
    }
  }
}

// ---------------------------------------------------------------------------
// LayerNorm over D=1024 (f32 input), one block per row.
// ---------------------------------------------------------------------------
template <bool SPLIT>
__global__ __launch_bounds__(256) void ln_kernel(
    const float* __restrict__ x, const float* __restrict__ g,
    const float* __restrict__ b, bf16* __restrict__ hi, bf16* __restrict__ lo) {
  const int row = blockIdx.x;
  const int tid = threadIdx.x;
  const float* xr = x + (size_t)row * 1024;
  float v[4];
  float s1 = 0.f, s2 = 0.f;
#pragma unroll
  for (int j = 0; j < 4; ++j) {
    v[j] = xr[j * 256 + tid];
    s1 += v[j];
    s2 += v[j] * v[j];
  }
#pragma unroll
  for (int off = 1; off < 64; off <<= 1) {
    s1 += __shfl_xor(s1, off);
    s2 += __shfl_xor(s2, off);
  }
  __shared__ float ws1[4], ws2[4];
  const int wid = tid >> 6;
  if ((tid & 63) == 0) {
    ws1[wid] = s1;
    ws2[wid] = s2;
  }
  __syncthreads();
  s1 = ws1[0] + ws1[1] + ws1[2] + ws1[3];
  s2 = ws2[0] + ws2[1] + ws2[2] + ws2[3];
  const float mu = s1 * (1.f / 1024.f);
  const float var = s2 * (1.f / 1024.f) - mu * mu;
  const float rstd = 1.0f / sqrtf(var + 1e-5f);
#pragma unroll
  for (int j = 0; j < 4; ++j) {
    const int cc = j * 256 + tid;
    const float y = (v[j] - mu) * rstd * g[cc] + b[cc];
    const bf16 yh = (bf16)y;
    hi[(size_t)row * 1024 + cc] = yh;
    if constexpr (SPLIT) lo[(size_t)row * 1024 + cc] = (bf16)(y - (float)yh);
  }
}

// ---------------------------------------------------------------------------
// MFMA causal flash attention, latency-optimized.
//  - Q fragments loaded straight from global (no Q LDS region)
//  - next K/V tile prefetched into registers during current tile's compute
//  - 2 barriers/iter; P tile wave-private (own region, stride 76, no barrier)
//  - softmax row reductions via DPP row_ror (VALU) — no LDS-pipe bpermutes
//  - LDS 37376 B -> 4 blocks/CU
//  - plain __launch_bounds__(256): (256,4) caused scratch spill — do not re-add
// Split-bf16 Q,K: S = qh*kh + qh*kl + ql*kh (lo*lo ~3e-3, below budget).
// Long blocks (qt=31) launched first to beat causal imbalance.
// ---------------------------------------------------------------------------
__global__ __launch_bounds__(256) void attn_kernel(
    const bf16* __restrict__ qh_g, const bf16* __restrict__ ql_g,
    const bf16* __restrict__ kh_g, const bf16* __restrict__ kl_g,
    const bf16* __restrict__ vt_g, bf16* __restrict__ out) {
  __shared__ bf16 lds[18688];  // 37376 B
  bf16* Kh = lds;              // 64 x 72
  bf16* Kl = lds + 4608;       // 64 x 72
  bf16* Vt = lds + 9216;       // 64 x 72, rows = dim d, cols = key
  bf16* Ps = lds + 13824;      // 64 x 76 (wave-private 16-row blocks)

  const int bid = blockIdx.x;
  const int qt = 31 - (bid >> 5);  // long blocks first
  const int h = bid & 15;
  const int b = (bid >> 4) & 1;
  const int t0 = qt << 6;
  const int tid = threadIdx.x;
  const int w = tid >> 6;
  const int lane = tid & 63;
  const int c = lane & 15;
  const int quad = lane >> 4;

  // staging map: chunk idx -> (row idx>>3, col8 (idx&7)*8)
  const int r0 = tid >> 3, c0 = (tid & 7) << 3;
  const int r1 = (tid + 256) >> 3, c1 = ((tid + 256) & 7) << 3;

  // Q fragments straight from global (once per block)
  const size_t qrow =
      ((size_t)(b * 2048 + t0 + w * 16 + c)) * 1024 + h * 64 + quad * 8;
  bf16x8 aqh[2], aql[2];
  aqh[0] = *(const bf16x8*)&qh_g[qrow];
  aqh[1] = *(const bf16x8*)&qh_g[qrow + 32];
  aql[0] = *(const bf16x8*)&ql_g[qrow];
  aql[1] = *(const bf16x8*)&ql_g[qrow + 32];

  f32x4 o[4];
  const f32x4 fzero = {0.f, 0.f, 0.f, 0.f};
#pragma unroll
  for (int j = 0; j < 4; ++j) o[j] = fzero;
  float m_i[4] = {-3e38f, -3e38f, -3e38f, -3e38f};
  float l_i[4] = {0.f, 0.f, 0.f, 0.f};

  const size_t vtb = ((size_t)(b * 16 + h)) * 64 * 2048;  // + d*2048 + t
  const size_t kband = ((size_t)(b * 2048)) * 1024 + h * 64;

  bf16x8 gk[6];  // register prefetch of next K/V tile
  {
    gk[0] = *(const bf16x8*)&kh_g[kband + (size_t)r0 * 1024 + c0];
    gk[1] = *(const bf16x8*)&kh_g[kband + (size_t)r1 * 1024 + c1];
    gk[2] = *(const bf16x8*)&kl_g[kband + (size_t)r0 * 1024 + c0];
    gk[3] = *(const bf16x8*)&kl_g[kband + (size_t)r1 * 1024 + c1];
    gk[4] = *(const bf16x8*)&vt_g[vtb + (size_t)r0 * 2048 + c0];
    gk[5] = *(const bf16x8*)&vt_g[vtb + (size_t)r1 * 2048 + c1];
  }

  for (int kt = 0; kt <= qt; ++kt) {
    __syncthreads();  // (A) prev tile's fragment reads done before restage
    *(bf16x8*)&Kh[r0 * 72 + c0] = gk[0];
    *(bf16x8*)&Kh[r1 * 72 + c1] = gk[1];
    *(bf16x8*)&Kl[r0 * 72 + c0] = gk[2];
    *(bf16x8*)&Kl[r1 * 72 + c1] = gk[3];
    *(bf16x8*)&Vt[r0 * 72 + c0] = gk[4];
    *(bf16x8*)&Vt[r1 * 72 + c1] = gk[5];
    __syncthreads();  // (B) staging visible

    if (kt < qt) {  // prefetch next tile; latency hidden behind compute
      const int kb1 = (kt + 1) << 6;
      const size_t kbase = kband + (size_t)kb1 * 1024;
      gk[0] = *(const bf16x8*)&kh_g[kbase + (size_t)r0 * 1024 + c0];
      gk[1] = *(const bf16x8*)&kh_g[kbase + (size_t)r1 * 1024 + c1];
      gk[2] = *(const bf16x8*)&kl_g[kbase + (size_t)r0 * 1024 + c0];
      gk[3] = *(const bf16x8*)&kl_g[kbase + (size_t)r1 * 1024 + c1];
      gk[4] = *(const bf16x8*)&vt_g[vtb + (size_t)r0 * 2048 + kb1 + c0];
      gk[5] = *(const bf16x8*)&vt_g[vtb + (size_t)r1 * 2048 + kb1 + c1];
    }

    bf16x8 bkh[4][2], bkl[4][2];
#pragma unroll
    for (int j = 0; j < 4; ++j)
#pragma unroll
      for (int s = 0; s < 2; ++s) {
        bkh[j][s] = *(const bf16x8*)&Kh[(j * 16 + c) * 72 + s * 32 + quad * 8];
        bkl[j][s] = *(const bf16x8*)&Kl[(j * 16 + c) * 72 + s * 32 + quad * 8];
      }

    f32x4 s4[4];
#pragma unroll
    for (int j = 0; j < 4; ++j) s4[j] = fzero;
#pragma unroll
    for (int j = 0; j < 4; ++j)
#pragma unroll
      for (int s = 0; s < 2; ++s) {
        s4[j] = __builtin_amdgcn_mfma_f32_16x16x32_bf16(aqh[s], bkh[j][s], s4[j], 0, 0, 0);
        s4[j] = __builtin_amdgcn_mfma_f32_16x16x32_bf16(aqh[s], bkl[j][s], s4[j], 0, 0, 0);
        s4[j] = __builtin_amdgcn_mfma_f32_16x16x32_bf16(aql[s], bkh[j][s], s4[j], 0, 0, 0);
      }

    if (kt == qt) {  // diagonal tile: strict-upper mask (t0 == kb)
#pragma unroll
      for (int j = 0; j < 4; ++j)
#pragma unroll
        for (int r = 0; r < 4; ++r)
          if (j * 16 + c > w * 16 + quad * 4 + r) s4[j][r] = -3e38f;
    }

    float al[4], p[4][4];
#pragma unroll
    for (int r = 0; r < 4; ++r) {
      float mt = fmaxf(fmaxf(s4[0][r], s4[1][r]), fmaxf(s4[2][r], s4[3][r]));
      mt = rowmax16(mt);  // DPP row reduce (16-lane row == c group)
      const float mn = fmaxf(m_i[r], mt);
      al[r] = __expf(m_i[r] - mn);
      float ps = 0.f;
#pragma unroll
      for (int j = 0; j < 4; ++j) {
        p[r][j] = __expf(s4[j][r] - mn);
        ps += p[r][j];
      }
      ps = rowsum16(ps);  // DPP row reduce
      l_i[r] = l_i[r] * al[r] + ps;
      m_i[r] = mn;
#pragma unroll
      for (int j = 0; j < 4; ++j) o[j][r] *= al[r];
    }

    // P -> wave-private region, stride 76 (conflict-free; intra-wave RAW only)
    bf16* Pw = Ps + w * 16 * 76;
#pragma unroll
    for (int r = 0; r < 4; ++r)
#pragma unroll
      for (int j = 0; j < 4; ++j)
        Pw[(quad * 4 + r) * 76 + j * 16 + c] = (bf16)p[r][j];

    bf16x8 ap[2], bv[4][2];
#pragma unroll
    for (int s = 0; s < 2; ++s)
      ap[s] = *(const bf16x8*)&Pw[c * 76 + s * 32 + quad * 8];
#pragma unroll
    for (int j = 0; j < 4; ++j)
#pragma unroll
      for (int s = 0; s < 2; ++s)
        bv[j][s] = *(const bf16x8*)&Vt[(j * 16 + c) * 72 + s * 32 + quad * 8];
#pragma unroll
    for (int j = 0; j < 4; ++j)
#pragma unroll
      for (int s = 0; s < 2; ++s)
        o[j] = __builtin_amdgcn_mfma_f32_16x16x32_bf16(ap[s], bv[j][s], o[j], 0, 0, 0);
  }

#pragma unroll
  for (int r = 0; r < 4; ++r) {
    const float inv = 1.0f / l_i[r];
#pragma unroll
    for (int j = 0; j < 4; ++j) {
      const size_t oi =
          ((size_t)(b * 2048 + t0 + w * 16 + quad * 4 + r)) * 1024 + h * 64 +
          j * 16 + c;
      out[oi] = (bf16)(o[j][r] * inv);
    }
  }
}

// ---------------------------------------------------------------------------
// Workspace plan (80 MiB peak; >104 MiB previously corrupted harness memory):
//   [ 0, 8)   Wq|Wk|Wv|Wo bf16
//   [ 8,24)   h_hi|h_lo  -> (after gemm_qkv) Wf1_b|Wf2_b   (cvt2 overwrite)
//   [24,40)   qh|ql      -> (after attn)   x1 (f32)
//   [40,72)   kh|kl|vt|attnout -> (after k4) ff (bf16 4096x4096)
//   [72,80)   h2
// ---------------------------------------------------------------------------
extern "C" void kernel_launch(void* const* d_in, const int* in_sizes, int n_in,
                              void* d_out, int out_size, void* d_ws,
                              size_t ws_size, hipStream_t stream) {
  const float* x = (const float*)d_in[0];
  const float* g1 = (const float*)d_in[2];
  const float* b1 = (const float*)d_in[3];
  const float* g2 = (const float*)d_in[4];
  const float* b2 = (const float*)d_in[5];
  const float* Wq = (const float*)d_in[6];
  const float* Wk = (const float*)d_in[7];
  const float* Wv = (const float*)d_in[8];
  const float* Wo = (const float*)d_in[9];
  const float* Wf1 = (const float*)d_in[10];
  const float* Wf2 = (const float*)d_in[11];
  char* ws = (char*)d_ws;
  const size_t MB = 1024 * 1024;
  const size_t M1 = 1u << 20;
  bf16* Wq_b = (bf16*)ws;
  bf16* Wk_b = Wq_b + 1 * M1;
  bf16* Wv_b = Wq_b + 2 * M1;
  bf16* Wo_b = Wq_b + 3 * M1;
  bf16* h_hi = (bf16*)(ws + 8 * MB);
  bf16* h_lo = (bf16*)(ws + 16 * MB);
  bf16* Wf1_b = h_hi;  // alias: h dead after gemm_qkv; cvt2 fills before k6
  bf16* Wf2_b = h_lo;
  bf16* qh = (bf16*)(ws + 24 * MB);
  bf16* ql = (bf16*)(ws + 32 * MB);
  bf16* kh = (bf16*)(ws + 40 * MB);
  bf16* kl = (bf16*)(ws + 48 * MB);
  bf16* vt = (bf16*)(ws + 56 * MB);
  bf16* attnout = (bf16*)(ws + 64 * MB);
  float* x1 = (float*)qh;  // alias: qh/ql dead after attn
  bf16* h2 = (bf16*)(ws + 72 * MB);
  bf16* ff = kh;  // alias: kh/kl/vt/attnout dead after k4
  float* outp = (float*)d_out;

  // 0) attention-path weights f32 -> bf16 (exact for ternary)
  cvt4<<<4096, 256, 0, stream>>>(Wq, Wk, Wv, Wo, Wq_b);
  // 1) LN1 -> split bf16 hi/lo
  ln_kernel<true><<<4096, 256, 0, stream>>>(x, g1, b1, h_hi, h_lo);
  // 2) Q,K (merged split bf16, q pre-scaled 1/8) + V^T (single-pass) fused
  gemm_qkv<<<dim3(24, 32), 256, 0, stream>>>(h_hi, h_lo, Wq_b, Wk_b, Wv_b, qh,
                                             ql, kh, kl, vt);
  // 2.5) h is dead now: convert FF weights into its slot
  cvt2<<<8192, 256, 0, stream>>>(Wf1, Wf2, Wf1_b);
  // 3) MFMA causal flash attention -> bf16 (B,T,1024)
  attn_kernel<<<1024, 256, 0, stream>>>(qh, ql, kh, kl, vt, attnout);
  // 4) x1 = x + attnout @ Wo^T   (f32; overwrites dead qh/ql) — 64N tiles
  gemm_bt64<2><<<dim3(16, 32), 256, 0, stream>>>(attnout, Wo_b, (void*)x1, x,
                                                 4096, 1024, 1024);
  // 5) LN2 -> h2 (bf16)
  ln_kernel<false><<<4096, 256, 0, stream>>>(x1, g2, b2, h2, nullptr);
  // 6) ff = gelu(h2 @ Wff1^T)  (bf16; overwrites dead kh/kl/vt/attnout)
  gemm_bt<3, false><<<dim3(32, 32), 256, 0, stream>>>(
      h2, nullptr, Wf1_b, (void*)ff, nullptr, 4096, 4096, 1024);
  // 7) out = x1 + ff @ Wff2^T  (f32) — 64N tiles
  gemm_bt64<2><<<dim3(16, 32), 256, 0, stream>>>(ff, Wf2_b, (void*)outp, x1,
                                                 4096, 1024, 4096);
}